// Round 3
// baseline (6084.523 us; speedup 1.0000x reference)
//
#include <hip/hip_runtime.h>
#include <hip/hip_cooperative_groups.h>
#include <math.h>

namespace cg = cooperative_groups;

// Problem dims
constexpr int Bsz  = 512;
constexpr int Nseq = 64;
constexpr int DX   = 4;
constexpr int MET  = 4;
constexpr int Hd   = 512;
constexpr int H3d  = 1536;

constexpr float RTOL_C = 1e-3f;
constexpr float ATOL_C = 1e-5f;

// ---- Dopri5 tableau (exactly as in jax.experimental.ode, f64->f32) ----
constexpr float SB10 = (float)(1.0/5.0);
constexpr float SB20 = (float)(3.0/40.0),  SB21 = (float)(9.0/40.0);
constexpr float SB30 = (float)(44.0/45.0), SB31 = (float)(-56.0/15.0), SB32 = (float)(32.0/9.0);
constexpr float SB40 = (float)(19372.0/6561.0), SB41 = (float)(-25360.0/2187.0),
                SB42 = (float)(64448.0/6561.0), SB43 = (float)(-212.0/729.0);
constexpr float SB50 = (float)(9017.0/3168.0),  SB51 = (float)(-355.0/33.0),
                SB52 = (float)(46732.0/5247.0), SB53 = (float)(49.0/176.0),
                SB54 = (float)(-5103.0/18656.0);
constexpr float CS0 = (float)(35.0/384.0), CS2 = (float)(500.0/1113.0),
                CS3 = (float)(125.0/192.0), CS4 = (float)(-2187.0/6784.0),
                CS5 = (float)(11.0/84.0);
// Shampine error coefficients (c_sol - c_star), as written in jax ode.py
constexpr float CE0 = (float)(35.0/384.0 - 1951.0/21600.0);
constexpr float CE2 = (float)(500.0/1113.0 - 22642.0/50085.0);
constexpr float CE3 = (float)(125.0/192.0 - 451.0/720.0);
constexpr float CE4 = (float)(-2187.0/6784.0 + 12231.0/42400.0);
constexpr float CE5 = (float)(11.0/84.0 - 649.0/6300.0);
constexpr float CE6 = (float)(-1.0/60.0);
// dps_c_mid for interpolation fit
constexpr float CM0 = (float)(6025192743.0/30085553152.0/2.0);
constexpr float CM2 = (float)(51252292925.0/65400821598.0/2.0);
constexpr float CM3 = (float)(-2691868925.0/45128329728.0/2.0);
constexpr float CM4 = (float)(187940372067.0/1594534317056.0/2.0);
constexpr float CM5 = (float)(-1776094331.0/19743644256.0/2.0);
constexpr float CM6 = (float)(11237099.0/235043384.0/2.0);

__device__ __forceinline__ float selu_f(float v) {
  const float scl = 1.0507009873554805f;
  const float alp = 1.6732632423543772f;
  float e = v > 0.f ? v : alp * expm1f(v);
  return scl * e;
}
__device__ __forceinline__ float sigmoid_f(float v) {
  return 1.f / (1.f + expf(-v));
}

// ---------------- weight repack kernels ----------------
// W: (R,K) row-major -> P[k/4][R][4] so inner k-loop uses one float4/row
__global__ void pack_kT4(const float* __restrict__ W, float* __restrict__ P, int R, int K) {
  int i = blockIdx.x * 256 + threadIdx.x;
  if (i >= R * K) return;
  int r = i / K, k = i % K;
  P[(k >> 2) * (R * 4) + r * 4 + (k & 3)] = W[i];
}
// plain transpose (R,C) -> (C,R)
__global__ void transpose_k(const float* __restrict__ W, float* __restrict__ T, int R, int C) {
  int i = blockIdx.x * 256 + threadIdx.x;
  if (i >= R * C) return;
  int r = i / C, c = i % C;
  T[c * R + r] = W[i];
}

// ---------------- persistent cooperative GRU ----------------
// One launch: 256 blocks x 512 threads (1 block/CU). Block = 16 batch rows x
// 64 j-cols. All 64 time steps inside with grid.sync() between them.
// Wih columns, biases, meta cached in registers for the whole sequence.
// (Replaces 64 serial launches that were latency/launch-overhead bound at
//  ~35us each vs a 5.1us VALU floor.)
__global__ __launch_bounds__(512) void gru_coop_kernel(
    const float* __restrict__ x, const float* __restrict__ meta,
    const float* __restrict__ WihT, const float* __restrict__ WhhP,
    const float* __restrict__ bih, const float* __restrict__ bhh,
    float* __restrict__ hA, float* __restrict__ hB)
{
  cg::grid_group grid = cg::this_grid();
  __shared__ __align__(16) float hs[16 * Hd];    // 32 KB h tile
  const int tid = threadIdx.x;
  const int jl  = tid & 63;
  const int rg  = tid >> 6;                      // wave id 0..7 -> rows rg*2, rg*2+1
  const int jt  = blockIdx.x & 7;
  const int bt  = blockIdx.x >> 3;
  const int j   = jt * 64 + jl;
  const int b0  = bt * 16;

  // cache input-projection weights + biases for this j across all steps
  float wir[8], wiz[8], win[8];
#pragma unroll
  for (int kk = 0; kk < 8; ++kk) {
    wir[kk] = WihT[kk * H3d + j];
    wiz[kk] = WihT[kk * H3d + 512 + j];
    win[kk] = WihT[kk * H3d + 1024 + j];
  }
  const float bihr = bih[j], bihz = bih[512 + j], bihn = bih[1024 + j];
  const float bhhr = bhh[j], bhhz = bhh[512 + j], bhhn = bhh[1024 + j];
  const float4 mv0 = *(const float4*)&meta[(b0 + rg * 2 + 0) * MET];
  const float4 mv1 = *(const float4*)&meta[(b0 + rg * 2 + 1) * MET];

  for (int t = 0; t < Nseq; ++t) {
    const float* hin = (t & 1) ? hB : hA;
    float* hout      = (t & 1) ? hA : hB;

    // stage this block's 16x512 h tile into LDS
    for (int i = tid; i < 16 * Hd / 4; i += 512)
      *(float4*)&hs[i * 4] = *(const float4*)&hin[b0 * Hd + i * 4];
    __syncthreads();

    float ar0 = 0.f, az0 = 0.f, an0 = 0.f;
    float ar1 = 0.f, az1 = 0.f, an1 = 0.f;
#pragma unroll 4
    for (int k4 = 0; k4 < Hd / 4; ++k4) {
      const float4 wr = *(const float4*)&WhhP[(k4 * H3d + j) * 4];
      const float4 wz = *(const float4*)&WhhP[(k4 * H3d + 512 + j) * 4];
      const float4 wn = *(const float4*)&WhhP[(k4 * H3d + 1024 + j) * 4];
      const float4 h0 = *(const float4*)&hs[(rg * 2 + 0) * Hd + k4 * 4];
      const float4 h1 = *(const float4*)&hs[(rg * 2 + 1) * Hd + k4 * 4];
      ar0 += wr.x * h0.x + wr.y * h0.y + wr.z * h0.z + wr.w * h0.w;
      az0 += wz.x * h0.x + wz.y * h0.y + wz.z * h0.z + wz.w * h0.w;
      an0 += wn.x * h0.x + wn.y * h0.y + wn.z * h0.z + wn.w * h0.w;
      ar1 += wr.x * h1.x + wr.y * h1.y + wr.z * h1.z + wr.w * h1.w;
      az1 += wz.x * h1.x + wz.y * h1.y + wz.z * h1.z + wz.w * h1.w;
      an1 += wn.x * h1.x + wn.y * h1.y + wn.z * h1.z + wn.w * h1.w;
    }

#pragma unroll
    for (int m = 0; m < 2; ++m) {
      const int bl = rg * 2 + m;
      const int b  = b0 + bl;
      const float4 xv = *(const float4*)&x[(b * Nseq + t) * DX];
      const float4 mv = m ? mv1 : mv0;
      float xm[8] = { xv.x, xv.y, xv.z, xv.w, mv.x, mv.y, mv.z, mv.w };
      float gr = bihr, gz = bihz, gn = bihn;
#pragma unroll
      for (int kk = 0; kk < 8; ++kk) {
        gr += xm[kk] * wir[kk];
        gz += xm[kk] * wiz[kk];
        gn += xm[kk] * win[kk];
      }
      const float ghr = (m ? ar1 : ar0) + bhhr;
      const float ghz = (m ? az1 : az0) + bhhz;
      const float ghn = (m ? an1 : an0) + bhhn;
      const float r = sigmoid_f(gr + ghr);
      const float z = sigmoid_f(gz + ghz);
      const float n = tanhf(gn + r * ghn);
      const float hold = hs[bl * Hd + j];
      hout[b * Hd + j] = (1.f - z) * n + z * hold;
    }

    grid.sync();
  }
}

// ---------------- encoder layer 1: relu(A @ W^T + b) ----------------
__global__ __launch_bounds__(256) void gemm_relu_kernel(
    const float* __restrict__ A, const float* __restrict__ WP,
    const float* __restrict__ bias, float* __restrict__ Cout)
{
  __shared__ __align__(16) float as[16 * Hd];
  const int tid  = threadIdx.x;
  const int jl   = tid & 63;
  const int bsub = tid >> 6;
  const int j    = blockIdx.y * 64 + jl;
  const int b0   = blockIdx.x * 16;

  for (int i = tid; i < 16 * Hd; i += 256) as[i] = A[b0 * Hd + i];
  __syncthreads();

  float acc[4] = {0.f, 0.f, 0.f, 0.f};
#pragma unroll 2
  for (int k4 = 0; k4 < Hd / 4; ++k4) {
    const float4 w = *(const float4*)&WP[(k4 * Hd + j) * 4];
#pragma unroll
    for (int m = 0; m < 4; ++m) {
      const float4 av = *(const float4*)&as[(bsub * 4 + m) * Hd + k4 * 4];
      acc[m] += w.x * av.x + w.y * av.y + w.z * av.z + w.w * av.w;
    }
  }
  const float bj = bias[j];
#pragma unroll
  for (int m = 0; m < 4; ++m) {
    const int b = b0 + bsub * 4 + m;
    float v = acc[m] + bj;
    Cout[b * Hd + j] = v > 0.f ? v : 0.f;
  }
}

// ---------------- encoder layer 2 + reparam: z0 = eps*std + mean ----------------
__global__ __launch_bounds__(256) void enc2_z0_kernel(
    const float* __restrict__ O1, const float* __restrict__ W2P,  // [k4][1024][4]
    const float* __restrict__ b2, const float* __restrict__ eps,
    float* __restrict__ z0)
{
  __shared__ __align__(16) float as[16 * Hd];
  const int tid  = threadIdx.x;
  const int jl   = tid & 63;
  const int bsub = tid >> 6;
  const int j    = blockIdx.y * 64 + jl;
  const int b0   = blockIdx.x * 16;

  for (int i = tid; i < 16 * Hd; i += 256) as[i] = O1[b0 * Hd + i];
  __syncthreads();

  float am[4] = {0.f, 0.f, 0.f, 0.f};
  float asd[4] = {0.f, 0.f, 0.f, 0.f};
#pragma unroll 2
  for (int k4 = 0; k4 < Hd / 4; ++k4) {
    const float4 wm = *(const float4*)&W2P[(k4 * 1024 + j) * 4];
    const float4 ws = *(const float4*)&W2P[(k4 * 1024 + 512 + j) * 4];
#pragma unroll
    for (int m = 0; m < 4; ++m) {
      const float4 av = *(const float4*)&as[(bsub * 4 + m) * Hd + k4 * 4];
      am[m]  += wm.x * av.x + wm.y * av.y + wm.z * av.z + wm.w * av.w;
      asd[m] += ws.x * av.x + ws.y * av.y + ws.z * av.z + ws.w * av.w;
    }
  }
  const float bm = b2[j], bs = b2[512 + j];
#pragma unroll
  for (int m = 0; m < 4; ++m) {
    const int b = b0 + bsub * 4 + m;
    const float mean = am[m] + bm;
    const float sd   = asd[m] + bs;
    z0[b * Hd + j] = eps[b * Hd + j] * sd + mean;
  }
}

// ---------------- adaptive Dopri5 ODE solve + final FC ----------------
// 128 blocks x 512 threads, GE=4 elements per block.
// Thread (jj, eh): computes outputs j in {jj, jj+256} for 2 of the 4 elements
// (eh*2, eh*2+1). Register-blocking j 2x halves LDS-pipe pressure (the R1/R2
// bottleneck: 1 LDS b128 per 4 FMAs -> now 4 LDS b64 per 16 FMAs).
// Slot map l in 0..3: j = (l>>1)? jj+256 : jj ; elem = eh*2 + (l&1).
__global__ __launch_bounds__(512) void ode_fc_kernel(
    const float* __restrict__ x, const float* __restrict__ meta,
    const float* __restrict__ z0in,
    const float* __restrict__ W1P, const float* __restrict__ b1v,
    const float* __restrict__ W2P, const float* __restrict__ b2v,
    const float* __restrict__ fcW, const float* __restrict__ fcb,
    float* __restrict__ outp)
{
  constexpr int GE = 4;
  __shared__ __align__(16) float zsh[Hd * GE];   // [k][elem], 8 KB
  __shared__ float red[8 * GE];
  const int tid = threadIdx.x;
  const int jj  = tid & 255;
  const int eh  = tid >> 8;            // wave-uniform (waves 0-3: 0, 4-7: 1)
  const int j1  = jj + 256;
  const int e0  = eh * 2;
  const int bg0 = blockIdx.x * GE;

  const float b1a = b1v[jj], b1b = b1v[j1];
  const float b2a = b2v[jj], b2b = b2v[j1];

  // drift for the thread's 4 (j,elem) slots
  auto drift = [&](const float (&in)[4], float (&out)[4]) {
    __syncthreads();
    *(float2*)&zsh[jj * 4 + e0] = make_float2(in[0], in[1]);
    *(float2*)&zsh[j1 * 4 + e0] = make_float2(in[2], in[3]);
    __syncthreads();
    float u[4] = { b1a, b1a, b1b, b1b };
#pragma unroll 4
    for (int k4 = 0; k4 < Hd / 4; ++k4) {
      const float4 wA = *(const float4*)&W1P[(k4 * Hd + jj) * 4];
      const float4 wB = *(const float4*)&W1P[(k4 * Hd + j1) * 4];
      const float2 za = *(const float2*)&zsh[(k4 * 4 + 0) * 4 + e0];
      const float2 zb = *(const float2*)&zsh[(k4 * 4 + 1) * 4 + e0];
      const float2 zc = *(const float2*)&zsh[(k4 * 4 + 2) * 4 + e0];
      const float2 zd = *(const float2*)&zsh[(k4 * 4 + 3) * 4 + e0];
      u[0] += wA.x * za.x + wA.y * zb.x + wA.z * zc.x + wA.w * zd.x;
      u[1] += wA.x * za.y + wA.y * zb.y + wA.z * zc.y + wA.w * zd.y;
      u[2] += wB.x * za.x + wB.y * zb.x + wB.z * zc.x + wB.w * zd.x;
      u[3] += wB.x * za.y + wB.y * zb.y + wB.z * zc.y + wB.w * zd.y;
    }
#pragma unroll
    for (int l = 0; l < 4; ++l) u[l] = selu_f(u[l]);
    __syncthreads();
    *(float2*)&zsh[jj * 4 + e0] = make_float2(u[0], u[1]);
    *(float2*)&zsh[j1 * 4 + e0] = make_float2(u[2], u[3]);
    __syncthreads();
    float v[4] = { b2a, b2a, b2b, b2b };
#pragma unroll 4
    for (int k4 = 0; k4 < Hd / 4; ++k4) {
      const float4 wA = *(const float4*)&W2P[(k4 * Hd + jj) * 4];
      const float4 wB = *(const float4*)&W2P[(k4 * Hd + j1) * 4];
      const float2 za = *(const float2*)&zsh[(k4 * 4 + 0) * 4 + e0];
      const float2 zb = *(const float2*)&zsh[(k4 * 4 + 1) * 4 + e0];
      const float2 zc = *(const float2*)&zsh[(k4 * 4 + 2) * 4 + e0];
      const float2 zd = *(const float2*)&zsh[(k4 * 4 + 3) * 4 + e0];
      v[0] += wA.x * za.x + wA.y * zb.x + wA.z * zc.x + wA.w * zd.x;
      v[1] += wA.x * za.y + wA.y * zb.y + wA.z * zc.y + wA.w * zd.y;
      v[2] += wB.x * za.x + wB.y * zb.x + wB.z * zc.x + wB.w * zd.x;
      v[3] += wB.x * za.y + wB.y * zb.y + wB.z * zc.y + wB.w * zd.y;
    }
#pragma unroll
    for (int l = 0; l < 4; ++l) out[l] = v[l];
  };

  // block-wide per-element sum; all threads receive identical results
  auto blocksum = [&](float (&v)[GE], float (&s)[GE]) {
#pragma unroll
    for (int off = 32; off > 0; off >>= 1) {
#pragma unroll
      for (int g = 0; g < GE; ++g) v[g] += __shfl_down(v[g], off);
    }
    __syncthreads();
    if ((tid & 63) == 0) {
      const int w = tid >> 6;
#pragma unroll
      for (int g = 0; g < GE; ++g) red[w * GE + g] = v[g];
    }
    __syncthreads();
#pragma unroll
    for (int g = 0; g < GE; ++g) {
      float t = 0.f;
#pragma unroll
      for (int w = 0; w < 8; ++w) t += red[w * GE + g];
      s[g] = t;
    }
  };

#define EL(l) (e0 + ((l) & 1))

  float y[4], f[4], py[4], pf[4], ym[4];
  float tcur[GE], dtv[GE], tfin[GE], ptv[GE], pdt[GE];
  bool act[GE];

  y[0] = z0in[(bg0 + e0 + 0) * Hd + jj];
  y[1] = z0in[(bg0 + e0 + 1) * Hd + jj];
  y[2] = z0in[(bg0 + e0 + 0) * Hd + j1];
  y[3] = z0in[(bg0 + e0 + 1) * Hd + j1];
#pragma unroll
  for (int g = 0; g < GE; ++g) {
    tcur[g] = x[((bg0 + g) * Nseq + 0) * DX];
    tfin[g] = x[((bg0 + g) * Nseq + (Nseq - 1)) * DX];
  }

  drift(y, f);

  // ---- initial step size (Hairer / jax variant) ----
  float sc[4];
  float q0[GE] = {0.f, 0.f, 0.f, 0.f}, q1[GE] = {0.f, 0.f, 0.f, 0.f};
#pragma unroll
  for (int l = 0; l < 4; ++l) {
    sc[l] = ATOL_C + RTOL_C * fabsf(y[l]);
    const float a = y[l] / sc[l], b = f[l] / sc[l];
    q0[EL(l)] += a * a;
    q1[EL(l)] += b * b;
  }
  float d0s[GE], d1s[GE];
  blocksum(q0, d0s);
  blocksum(q1, d1s);
  float h0[GE];
#pragma unroll
  for (int g = 0; g < GE; ++g) {
    const float d0 = sqrtf(d0s[g]), d1 = sqrtf(d1s[g]);
    h0[g] = (d0 < 1e-5f || d1 < 1e-5f) ? 1e-6f : 0.01f * d0 / d1;
  }
  float yin[4], f1h[4];
#pragma unroll
  for (int l = 0; l < 4; ++l) yin[l] = y[l] + h0[EL(l)] * f[l];
  drift(yin, f1h);
  float q2[GE] = {0.f, 0.f, 0.f, 0.f};
#pragma unroll
  for (int l = 0; l < 4; ++l) {
    const float dd = (f1h[l] - f[l]) / sc[l];
    q2[EL(l)] += dd * dd;
  }
  float d2s[GE];
  blocksum(q2, d2s);
#pragma unroll
  for (int g = 0; g < GE; ++g) {
    const float d1 = sqrtf(d1s[g]);
    const float d2 = sqrtf(d2s[g]) / h0[g];
    const float h1 = (d1 <= 1e-15f && d2 <= 1e-15f)
                 ? fmaxf(1e-6f, h0[g] * 1e-3f)
                 : powf(0.01f / (d1 + d2), 0.2f);   // jax uses d1+d2 here
    dtv[g] = fminf(100.f * h0[g], h1);
    ptv[g] = tcur[g]; pdt[g] = dtv[g];
    act[g] = (tcur[g] < tfin[g]) && (dtv[g] > 0.f);
  }
#pragma unroll
  for (int l = 0; l < 4; ++l) { py[l] = y[l]; pf[l] = f[l]; ym[l] = y[l]; }

  // ---- adaptive stepping loop ----
  float k2[4], k3[4], k4v[4], k5[4], k6[4], k7[4], y1v[4];
  for (int iter = 0; iter < 4000; ++iter) {
    bool anyact = false;
#pragma unroll
    for (int g = 0; g < GE; ++g) anyact = anyact || act[g];
    if (!anyact) break;

#pragma unroll
    for (int l = 0; l < 4; ++l) yin[l] = y[l] + dtv[EL(l)] * (SB10 * f[l]);
    drift(yin, k2);

#pragma unroll
    for (int l = 0; l < 4; ++l)
      yin[l] = y[l] + dtv[EL(l)] * (SB20 * f[l] + SB21 * k2[l]);
    drift(yin, k3);

#pragma unroll
    for (int l = 0; l < 4; ++l)
      yin[l] = y[l] + dtv[EL(l)] * (SB30 * f[l] + SB31 * k2[l] + SB32 * k3[l]);
    drift(yin, k4v);

#pragma unroll
    for (int l = 0; l < 4; ++l)
      yin[l] = y[l] + dtv[EL(l)] * (SB40 * f[l] + SB41 * k2[l] + SB42 * k3[l] + SB43 * k4v[l]);
    drift(yin, k5);

#pragma unroll
    for (int l = 0; l < 4; ++l)
      yin[l] = y[l] + dtv[EL(l)] * (SB50 * f[l] + SB51 * k2[l] + SB52 * k3[l] + SB53 * k4v[l] + SB54 * k5[l]);
    drift(yin, k6);

#pragma unroll
    for (int l = 0; l < 4; ++l)
      y1v[l] = y[l] + dtv[EL(l)] * (CS0 * f[l] + CS2 * k3[l] + CS3 * k4v[l] + CS4 * k5[l] + CS5 * k6[l]);
    drift(y1v, k7);

    float rs[GE] = {0.f, 0.f, 0.f, 0.f};
#pragma unroll
    for (int l = 0; l < 4; ++l) {
      const float yerr = dtv[EL(l)] * (CE0 * f[l] + CE2 * k3[l] + CE3 * k4v[l] + CE4 * k5[l] + CE5 * k6[l] + CE6 * k7[l]);
      const float tol = ATOL_C + RTOL_C * fmaxf(fabsf(y[l]), fabsf(y1v[l]));
      const float r = yerr / tol;
      rs[EL(l)] += r * r;
    }
    float rsum[GE];
    blocksum(rs, rsum);

    bool acc[GE];
#pragma unroll
    for (int g = 0; g < GE; ++g) {
      acc[g] = act[g] && (sqrtf(rsum[g] * (1.0f / Hd)) <= 1.0f);
    }
#pragma unroll
    for (int l = 0; l < 4; ++l) {
      const int g = EL(l);
      if (acc[g]) {
        ym[l] = y[l] + dtv[g] * (CM0 * f[l] + CM2 * k3[l] + CM3 * k4v[l] + CM4 * k5[l] + CM5 * k6[l] + CM6 * k7[l]);
        py[l] = y[l]; pf[l] = f[l];
        y[l] = y1v[l]; f[l] = k7[l];
      }
    }
#pragma unroll
    for (int g = 0; g < GE; ++g) {
      if (!act[g]) continue;
      const float er = sqrtf(rsum[g] * (1.0f / Hd));
      if (acc[g]) {
        ptv[g] = tcur[g]; pdt[g] = dtv[g];
        tcur[g] = tcur[g] + dtv[g];
      }
      float dtn;
      if (er == 0.0f) {
        dtn = dtv[g] * 10.0f;
      } else {
        const float dfac = (er < 1.0f) ? 1.0f : 0.2f;
        const float fac = fminf(10.0f, fmaxf(0.9f * powf(er, -0.2f), dfac));
        dtn = dtv[g] * fac;
      }
      dtv[g] = fmaxf(dtn, 0.0f);
      act[g] = (tcur[g] < tfin[g]) && (dtv[g] > 0.0f);
    }
  }

  // ---- interpolate at t_final (4th-order fit) and fused FC ----
  const float fcwA = fcW[jj];
  const float fcwB = fcW[j1];
  float s[GE] = {0.f, 0.f, 0.f, 0.f};
#pragma unroll
  for (int l = 0; l < 4; ++l) {
    const int g = EL(l);
    const float denom = tcur[g] - ptv[g];
    const float xr = (tfin[g] - ptv[g]) / denom;
    const float dy0 = pdt[g] * pf[l];
    const float dy1 = pdt[g] * f[l];
    const float aa = -2.f * dy0 + 2.f * dy1 - 8.f * py[l] - 8.f * y[l] + 16.f * ym[l];
    const float bb =  5.f * dy0 - 3.f * dy1 + 18.f * py[l] + 14.f * y[l] - 32.f * ym[l];
    const float cc = -4.f * dy0 + 1.f * dy1 - 11.f * py[l] - 5.f * y[l] + 16.f * ym[l];
    const float dd = dy0;
    const float ee = py[l];
    const float yf = (((aa * xr + bb) * xr + cc) * xr + dd) * xr + ee;
    s[g] += yf * ((l >> 1) ? fcwB : fcwA);
  }
  float ssum[GE];
  blocksum(s, ssum);
  if (tid == 0) {
#pragma unroll
    for (int g = 0; g < GE; ++g) {
      float o = ssum[g] + fcb[0];
#pragma unroll
      for (int m = 0; m < MET; ++m) o += meta[(bg0 + g) * MET + m] * fcW[Hd + m];
      outp[bg0 + g] = o;
    }
  }
#undef EL
}

// ---------------- host launcher ----------------
extern "C" void kernel_launch(void* const* d_in, const int* in_sizes, int n_in,
                              void* d_out, int out_size, void* d_ws, size_t ws_size,
                              hipStream_t stream)
{
  (void)in_sizes; (void)n_in; (void)out_size; (void)ws_size;

  const float* x    = (const float*)d_in[0];
  const float* meta = (const float*)d_in[1];
  const float* eps  = (const float*)d_in[2];
  const float* gWih = (const float*)d_in[3];
  const float* gWhh = (const float*)d_in[4];
  const float* gbih = (const float*)d_in[5];
  const float* gbhh = (const float*)d_in[6];
  const float* eW1  = (const float*)d_in[7];
  const float* eb1  = (const float*)d_in[8];
  const float* eW2  = (const float*)d_in[9];
  const float* eb2  = (const float*)d_in[10];
  const float* oW1  = (const float*)d_in[11];
  const float* ob1  = (const float*)d_in[12];
  const float* oW2  = (const float*)d_in[13];
  const float* ob2  = (const float*)d_in[14];
  const float* fcW  = (const float*)d_in[15];
  const float* fcb  = (const float*)d_in[16];
  float* out = (float*)d_out;
  float* ws  = (float*)d_ws;

  // ws layout (floats)
  float* WhhP = ws + 0;          //  786432
  float* WihT = ws + 786432;     //   12288
  float* eW1P = ws + 798720;     //  262144
  float* eW2P = ws + 1060864;    //  524288
  float* oW1P = ws + 1585152;    //  262144
  float* oW2P = ws + 1847296;    //  262144
  float* hA   = ws + 2109440;    //  262144 (h ping / z0)
  float* hB   = ws + 2371584;    //  262144 (h pong / o1)

  pack_kT4<<<(H3d * Hd + 255) / 256, 256, 0, stream>>>(gWhh, WhhP, H3d, Hd);
  transpose_k<<<(H3d * 8 + 255) / 256, 256, 0, stream>>>(gWih, WihT, H3d, 8);
  pack_kT4<<<(Hd * Hd + 255) / 256, 256, 0, stream>>>(eW1, eW1P, Hd, Hd);
  pack_kT4<<<(1024 * Hd + 255) / 256, 256, 0, stream>>>(eW2, eW2P, 1024, Hd);
  pack_kT4<<<(Hd * Hd + 255) / 256, 256, 0, stream>>>(oW1, oW1P, Hd, Hd);
  pack_kT4<<<(Hd * Hd + 255) / 256, 256, 0, stream>>>(oW2, oW2P, Hd, Hd);
  hipMemsetAsync(hA, 0, (size_t)Bsz * Hd * sizeof(float), stream);

  // persistent cooperative GRU: all 64 steps, grid-synced
  {
    void* args[] = { (void*)&x, (void*)&meta, (void*)&WihT, (void*)&WhhP,
                     (void*)&gbih, (void*)&gbhh, (void*)&hA, (void*)&hB };
    hipLaunchCooperativeKernel((const void*)gru_coop_kernel,
                               dim3(256), dim3(512), args, 0, stream);
  }
  // final h in hA (t=63 writes hA)
  dim3 egrid(32, 8);
  gemm_relu_kernel<<<egrid, 256, 0, stream>>>(hA, eW1P, eb1, hB);           // o1 -> hB
  enc2_z0_kernel<<<egrid, 256, 0, stream>>>(hB, eW2P, eb2, eps, hA);        // z0 -> hA
  ode_fc_kernel<<<Bsz / 4, 512, 0, stream>>>(x, meta, hA, oW1P, ob1, oW2P, ob2, fcW, fcb, out);
}

// Round 4
// 5310.361 us; speedup vs baseline: 1.1458x; 1.1458x over previous
//
#include <hip/hip_runtime.h>
#include <hip/hip_cooperative_groups.h>
#include <math.h>

namespace cg = cooperative_groups;

// Problem dims
constexpr int Bsz  = 512;
constexpr int Nseq = 64;
constexpr int DX   = 4;
constexpr int MET  = 4;
constexpr int Hd   = 512;
constexpr int H3d  = 1536;

constexpr float RTOL_C = 1e-3f;
constexpr float ATOL_C = 1e-5f;

// ---- Dopri5 tableau (exactly as in jax.experimental.ode, f64->f32) ----
constexpr float SB10 = (float)(1.0/5.0);
constexpr float SB20 = (float)(3.0/40.0),  SB21 = (float)(9.0/40.0);
constexpr float SB30 = (float)(44.0/45.0), SB31 = (float)(-56.0/15.0), SB32 = (float)(32.0/9.0);
constexpr float SB40 = (float)(19372.0/6561.0), SB41 = (float)(-25360.0/2187.0),
                SB42 = (float)(64448.0/6561.0), SB43 = (float)(-212.0/729.0);
constexpr float SB50 = (float)(9017.0/3168.0),  SB51 = (float)(-355.0/33.0),
                SB52 = (float)(46732.0/5247.0), SB53 = (float)(49.0/176.0),
                SB54 = (float)(-5103.0/18656.0);
constexpr float CS0 = (float)(35.0/384.0), CS2 = (float)(500.0/1113.0),
                CS3 = (float)(125.0/192.0), CS4 = (float)(-2187.0/6784.0),
                CS5 = (float)(11.0/84.0);
// Shampine error coefficients (c_sol - c_star), as written in jax ode.py
constexpr float CE0 = (float)(35.0/384.0 - 1951.0/21600.0);
constexpr float CE2 = (float)(500.0/1113.0 - 22642.0/50085.0);
constexpr float CE3 = (float)(125.0/192.0 - 451.0/720.0);
constexpr float CE4 = (float)(-2187.0/6784.0 + 12231.0/42400.0);
constexpr float CE5 = (float)(11.0/84.0 - 649.0/6300.0);
constexpr float CE6 = (float)(-1.0/60.0);
// dps_c_mid for interpolation fit
constexpr float CM0 = (float)(6025192743.0/30085553152.0/2.0);
constexpr float CM2 = (float)(51252292925.0/65400821598.0/2.0);
constexpr float CM3 = (float)(-2691868925.0/45128329728.0/2.0);
constexpr float CM4 = (float)(187940372067.0/1594534317056.0/2.0);
constexpr float CM5 = (float)(-1776094331.0/19743644256.0/2.0);
constexpr float CM6 = (float)(11237099.0/235043384.0/2.0);

__device__ __forceinline__ float selu_f(float v) {
  const float scl = 1.0507009873554805f;
  const float alp = 1.6732632423543772f;
  float e = v > 0.f ? v : alp * expm1f(v);
  return scl * e;
}
__device__ __forceinline__ float sigmoid_f(float v) {
  return 1.f / (1.f + expf(-v));
}

// ---------------- weight repack kernels ----------------
// W: (R,K) row-major -> P[k/4][R][4] so inner k-loop uses one float4/row
__global__ void pack_kT4(const float* __restrict__ W, float* __restrict__ P, int R, int K) {
  int i = blockIdx.x * 256 + threadIdx.x;
  if (i >= R * K) return;
  int r = i / K, k = i % K;
  P[(k >> 2) * (R * 4) + r * 4 + (k & 3)] = W[i];
}
// plain transpose (R,C) -> (C,R)
__global__ void transpose_k(const float* __restrict__ W, float* __restrict__ T, int R, int C) {
  int i = blockIdx.x * 256 + threadIdx.x;
  if (i >= R * C) return;
  int r = i / C, c = i % C;
  T[c * R + r] = W[i];
}

// ---------------- persistent cooperative GRU ----------------
// 256 blocks x 512 threads (1 block/CU). Block = 16 batch rows x 64 j-cols.
// XCD-locality swizzle: R3's FETCH_SIZE=235MB (3.7MB/step HBM refetch of the
// 3MB weight set) showed blocks are placed DEPTH-FIRST (blocks 0-31 share an
// XCD). With jt = bid>>5, all 32 blocks on one XCD read the SAME 393KB weight
// slice -> L2-resident across all 64 steps; h ping-pong (2MB/step) via L3.
__global__ __launch_bounds__(512) void gru_coop_kernel(
    const float* __restrict__ x, const float* __restrict__ meta,
    const float* __restrict__ WihT, const float* __restrict__ WhhP,
    const float* __restrict__ bih, const float* __restrict__ bhh,
    float* __restrict__ hA, float* __restrict__ hB)
{
  cg::grid_group grid = cg::this_grid();
  __shared__ __align__(16) float hs[16 * Hd];    // 32 KB h tile
  const int tid = threadIdx.x;
  const int jl  = tid & 63;
  const int rg  = tid >> 6;                      // wave id 0..7 -> rows rg*2, rg*2+1
  const int jt  = blockIdx.x >> 5;               // j-tile == XCD (depth-first placement)
  const int bt  = blockIdx.x & 31;               // batch tile within XCD
  const int j   = jt * 64 + jl;
  const int b0  = bt * 16;

  // cache input-projection weights + biases for this j across all steps
  float wir[8], wiz[8], win[8];
#pragma unroll
  for (int kk = 0; kk < 8; ++kk) {
    wir[kk] = WihT[kk * H3d + j];
    wiz[kk] = WihT[kk * H3d + 512 + j];
    win[kk] = WihT[kk * H3d + 1024 + j];
  }
  const float bihr = bih[j], bihz = bih[512 + j], bihn = bih[1024 + j];
  const float bhhr = bhh[j], bhhz = bhh[512 + j], bhhn = bhh[1024 + j];
  const float4 mv0 = *(const float4*)&meta[(b0 + rg * 2 + 0) * MET];
  const float4 mv1 = *(const float4*)&meta[(b0 + rg * 2 + 1) * MET];

  for (int t = 0; t < Nseq; ++t) {
    const float* hin = (t & 1) ? hB : hA;
    float* hout      = (t & 1) ? hA : hB;

    // stage this block's 16x512 h tile into LDS
    for (int i = tid; i < 16 * Hd / 4; i += 512)
      *(float4*)&hs[i * 4] = *(const float4*)&hin[b0 * Hd + i * 4];
    __syncthreads();

    float ar0 = 0.f, az0 = 0.f, an0 = 0.f;
    float ar1 = 0.f, az1 = 0.f, an1 = 0.f;
#pragma unroll 4
    for (int k4 = 0; k4 < Hd / 4; ++k4) {
      const float4 wr = *(const float4*)&WhhP[(k4 * H3d + j) * 4];
      const float4 wz = *(const float4*)&WhhP[(k4 * H3d + 512 + j) * 4];
      const float4 wn = *(const float4*)&WhhP[(k4 * H3d + 1024 + j) * 4];
      const float4 h0 = *(const float4*)&hs[(rg * 2 + 0) * Hd + k4 * 4];
      const float4 h1 = *(const float4*)&hs[(rg * 2 + 1) * Hd + k4 * 4];
      ar0 += wr.x * h0.x + wr.y * h0.y + wr.z * h0.z + wr.w * h0.w;
      az0 += wz.x * h0.x + wz.y * h0.y + wz.z * h0.z + wz.w * h0.w;
      an0 += wn.x * h0.x + wn.y * h0.y + wn.z * h0.z + wn.w * h0.w;
      ar1 += wr.x * h1.x + wr.y * h1.y + wr.z * h1.z + wr.w * h1.w;
      az1 += wz.x * h1.x + wz.y * h1.y + wz.z * h1.z + wz.w * h1.w;
      an1 += wn.x * h1.x + wn.y * h1.y + wn.z * h1.z + wn.w * h1.w;
    }

#pragma unroll
    for (int m = 0; m < 2; ++m) {
      const int bl = rg * 2 + m;
      const int b  = b0 + bl;
      const float4 xv = *(const float4*)&x[(b * Nseq + t) * DX];
      const float4 mv = m ? mv1 : mv0;
      float xm[8] = { xv.x, xv.y, xv.z, xv.w, mv.x, mv.y, mv.z, mv.w };
      float gr = bihr, gz = bihz, gn = bihn;
#pragma unroll
      for (int kk = 0; kk < 8; ++kk) {
        gr += xm[kk] * wir[kk];
        gz += xm[kk] * wiz[kk];
        gn += xm[kk] * win[kk];
      }
      const float ghr = (m ? ar1 : ar0) + bhhr;
      const float ghz = (m ? az1 : az0) + bhhz;
      const float ghn = (m ? an1 : an0) + bhhn;
      const float r = sigmoid_f(gr + ghr);
      const float z = sigmoid_f(gz + ghz);
      const float n = tanhf(gn + r * ghn);
      const float hold = hs[bl * Hd + j];
      hout[b * Hd + j] = (1.f - z) * n + z * hold;
    }

    if (t < Nseq - 1) grid.sync();
  }
}

// ---------------- encoder layer 1: relu(A @ W^T + b) ----------------
__global__ __launch_bounds__(256) void gemm_relu_kernel(
    const float* __restrict__ A, const float* __restrict__ WP,
    const float* __restrict__ bias, float* __restrict__ Cout)
{
  __shared__ __align__(16) float as[16 * Hd];
  const int tid  = threadIdx.x;
  const int jl   = tid & 63;
  const int bsub = tid >> 6;
  const int j    = blockIdx.y * 64 + jl;
  const int b0   = blockIdx.x * 16;

  for (int i = tid; i < 16 * Hd; i += 256) as[i] = A[b0 * Hd + i];
  __syncthreads();

  float acc[4] = {0.f, 0.f, 0.f, 0.f};
#pragma unroll 2
  for (int k4 = 0; k4 < Hd / 4; ++k4) {
    const float4 w = *(const float4*)&WP[(k4 * Hd + j) * 4];
#pragma unroll
    for (int m = 0; m < 4; ++m) {
      const float4 av = *(const float4*)&as[(bsub * 4 + m) * Hd + k4 * 4];
      acc[m] += w.x * av.x + w.y * av.y + w.z * av.z + w.w * av.w;
    }
  }
  const float bj = bias[j];
#pragma unroll
  for (int m = 0; m < 4; ++m) {
    const int b = b0 + bsub * 4 + m;
    float v = acc[m] + bj;
    Cout[b * Hd + j] = v > 0.f ? v : 0.f;
  }
}

// ---------------- encoder layer 2 + reparam: z0 = eps*std + mean ----------------
__global__ __launch_bounds__(256) void enc2_z0_kernel(
    const float* __restrict__ O1, const float* __restrict__ W2P,  // [k4][1024][4]
    const float* __restrict__ b2, const float* __restrict__ eps,
    float* __restrict__ z0)
{
  __shared__ __align__(16) float as[16 * Hd];
  const int tid  = threadIdx.x;
  const int jl   = tid & 63;
  const int bsub = tid >> 6;
  const int j    = blockIdx.y * 64 + jl;
  const int b0   = blockIdx.x * 16;

  for (int i = tid; i < 16 * Hd; i += 256) as[i] = O1[b0 * Hd + i];
  __syncthreads();

  float am[4] = {0.f, 0.f, 0.f, 0.f};
  float asd[4] = {0.f, 0.f, 0.f, 0.f};
#pragma unroll 2
  for (int k4 = 0; k4 < Hd / 4; ++k4) {
    const float4 wm = *(const float4*)&W2P[(k4 * 1024 + j) * 4];
    const float4 ws = *(const float4*)&W2P[(k4 * 1024 + 512 + j) * 4];
#pragma unroll
    for (int m = 0; m < 4; ++m) {
      const float4 av = *(const float4*)&as[(bsub * 4 + m) * Hd + k4 * 4];
      am[m]  += wm.x * av.x + wm.y * av.y + wm.z * av.z + wm.w * av.w;
      asd[m] += ws.x * av.x + ws.y * av.y + ws.z * av.z + ws.w * av.w;
    }
  }
  const float bm = b2[j], bs = b2[512 + j];
#pragma unroll
  for (int m = 0; m < 4; ++m) {
    const int b = b0 + bsub * 4 + m;
    const float mean = am[m] + bm;
    const float sd   = asd[m] + bs;
    z0[b * Hd + j] = eps[b * Hd + j] * sd + mean;
  }
}

// ---------------- adaptive Dopri5 ODE solve + final FC ----------------
// 256 blocks x 512 threads, GE=2 elements per block (all 256 CUs active).
// Thread (jj = tid&255, eh = tid>>8): owns outputs j in {jj, jj+256} for
// element eh. zsh is [e][k] so the k-loop reads one broadcast ds_read_b128
// per 8 FMA. Per-(j,e) k-accumulation order identical to previous rounds ->
// bit-identical trajectories. Control state for BOTH elements is replicated
// in every thread (derived from block-uniform reductions only).
__global__ __launch_bounds__(512) void ode_fc_kernel(
    const float* __restrict__ x, const float* __restrict__ meta,
    const float* __restrict__ z0in,
    const float* __restrict__ W1P, const float* __restrict__ b1v,
    const float* __restrict__ W2P, const float* __restrict__ b2v,
    const float* __restrict__ fcW, const float* __restrict__ fcb,
    float* __restrict__ outp)
{
  constexpr int GE = 2;
  __shared__ __align__(16) float zsh[GE][Hd];   // 4 KB
  __shared__ float red[8 * GE];
  const int tid = threadIdx.x;
  const int jj  = tid & 255;
  const int eh  = tid >> 8;            // element 0/1 (wave-uniform)
  const int j1  = jj + 256;
  const int bg0 = blockIdx.x * GE;

  const float b1a = b1v[jj], b1b = b1v[j1];
  const float b2a = b2v[jj], b2b = b2v[j1];

  // drift for the thread's 2 (j, eh) slots
  auto drift = [&](const float (&in)[2], float (&out)[2]) {
    __syncthreads();
    zsh[eh][jj] = in[0];
    zsh[eh][j1] = in[1];
    __syncthreads();
    float u0 = b1a, u1 = b1b;
#pragma unroll 4
    for (int k4 = 0; k4 < Hd / 4; ++k4) {
      const float4 wA = *(const float4*)&W1P[(k4 * Hd + jj) * 4];
      const float4 wB = *(const float4*)&W1P[(k4 * Hd + j1) * 4];
      const float4 z  = *(const float4*)&zsh[eh][k4 * 4];
      u0 += wA.x * z.x + wA.y * z.y + wA.z * z.z + wA.w * z.w;
      u1 += wB.x * z.x + wB.y * z.y + wB.z * z.z + wB.w * z.w;
    }
    u0 = selu_f(u0); u1 = selu_f(u1);
    __syncthreads();
    zsh[eh][jj] = u0;
    zsh[eh][j1] = u1;
    __syncthreads();
    float v0 = b2a, v1 = b2b;
#pragma unroll 4
    for (int k4 = 0; k4 < Hd / 4; ++k4) {
      const float4 wA = *(const float4*)&W2P[(k4 * Hd + jj) * 4];
      const float4 wB = *(const float4*)&W2P[(k4 * Hd + j1) * 4];
      const float4 z  = *(const float4*)&zsh[eh][k4 * 4];
      v0 += wA.x * z.x + wA.y * z.y + wA.z * z.z + wA.w * z.w;
      v1 += wB.x * z.x + wB.y * z.y + wB.z * z.z + wB.w * z.w;
    }
    out[0] = v0; out[1] = v1;
  };

  // block-wide per-element sum; all threads receive identical results
  auto blocksum = [&](float (&v)[GE], float (&s)[GE]) {
#pragma unroll
    for (int off = 32; off > 0; off >>= 1) {
#pragma unroll
      for (int g = 0; g < GE; ++g) v[g] += __shfl_down(v[g], off);
    }
    __syncthreads();
    if ((tid & 63) == 0) {
      const int w = tid >> 6;
#pragma unroll
      for (int g = 0; g < GE; ++g) red[w * GE + g] = v[g];
    }
    __syncthreads();
#pragma unroll
    for (int g = 0; g < GE; ++g) {
      float t = 0.f;
#pragma unroll
      for (int w = 0; w < 8; ++w) t += red[w * GE + g];
      s[g] = t;
    }
  };

  float y[2], f[2], py[2], pf[2], ym[2];
  float tcur[GE], dtv[GE], tfin[GE], ptv[GE], pdt[GE];
  bool act[GE];

  y[0] = z0in[(bg0 + eh) * Hd + jj];
  y[1] = z0in[(bg0 + eh) * Hd + j1];
#pragma unroll
  for (int g = 0; g < GE; ++g) {
    tcur[g] = x[((bg0 + g) * Nseq + 0) * DX];
    tfin[g] = x[((bg0 + g) * Nseq + (Nseq - 1)) * DX];
  }

  drift(y, f);

  // ---- initial step size (Hairer / jax variant) ----
  float sc[2];
  float q0[GE] = {0.f, 0.f}, q1[GE] = {0.f, 0.f};
#pragma unroll
  for (int l = 0; l < 2; ++l) {
    sc[l] = ATOL_C + RTOL_C * fabsf(y[l]);
    const float a = y[l] / sc[l], b = f[l] / sc[l];
    q0[eh] += a * a;
    q1[eh] += b * b;
  }
  float d0s[GE], d1s[GE];
  blocksum(q0, d0s);
  blocksum(q1, d1s);
  float h0[GE];
#pragma unroll
  for (int g = 0; g < GE; ++g) {
    const float d0 = sqrtf(d0s[g]), d1 = sqrtf(d1s[g]);
    h0[g] = (d0 < 1e-5f || d1 < 1e-5f) ? 1e-6f : 0.01f * d0 / d1;
  }
  float yin[2], f1h[2];
#pragma unroll
  for (int l = 0; l < 2; ++l) yin[l] = y[l] + h0[eh] * f[l];
  drift(yin, f1h);
  float q2[GE] = {0.f, 0.f};
#pragma unroll
  for (int l = 0; l < 2; ++l) {
    const float dd = (f1h[l] - f[l]) / sc[l];
    q2[eh] += dd * dd;
  }
  float d2s[GE];
  blocksum(q2, d2s);
#pragma unroll
  for (int g = 0; g < GE; ++g) {
    const float d1 = sqrtf(d1s[g]);
    const float d2 = sqrtf(d2s[g]) / h0[g];
    const float h1 = (d1 <= 1e-15f && d2 <= 1e-15f)
                 ? fmaxf(1e-6f, h0[g] * 1e-3f)
                 : powf(0.01f / (d1 + d2), 0.2f);   // jax uses d1+d2 here
    dtv[g] = fminf(100.f * h0[g], h1);
    ptv[g] = tcur[g]; pdt[g] = dtv[g];
    act[g] = (tcur[g] < tfin[g]) && (dtv[g] > 0.f);
  }
#pragma unroll
  for (int l = 0; l < 2; ++l) { py[l] = y[l]; pf[l] = f[l]; ym[l] = y[l]; }

  // ---- adaptive stepping loop ----
  float k2[2], k3[2], k4v[2], k5[2], k6[2], k7[2], y1v[2];
  for (int iter = 0; iter < 4000; ++iter) {
    if (!(act[0] || act[1])) break;

#pragma unroll
    for (int l = 0; l < 2; ++l) yin[l] = y[l] + dtv[eh] * (SB10 * f[l]);
    drift(yin, k2);

#pragma unroll
    for (int l = 0; l < 2; ++l)
      yin[l] = y[l] + dtv[eh] * (SB20 * f[l] + SB21 * k2[l]);
    drift(yin, k3);

#pragma unroll
    for (int l = 0; l < 2; ++l)
      yin[l] = y[l] + dtv[eh] * (SB30 * f[l] + SB31 * k2[l] + SB32 * k3[l]);
    drift(yin, k4v);

#pragma unroll
    for (int l = 0; l < 2; ++l)
      yin[l] = y[l] + dtv[eh] * (SB40 * f[l] + SB41 * k2[l] + SB42 * k3[l] + SB43 * k4v[l]);
    drift(yin, k5);

#pragma unroll
    for (int l = 0; l < 2; ++l)
      yin[l] = y[l] + dtv[eh] * (SB50 * f[l] + SB51 * k2[l] + SB52 * k3[l] + SB53 * k4v[l] + SB54 * k5[l]);
    drift(yin, k6);

#pragma unroll
    for (int l = 0; l < 2; ++l)
      y1v[l] = y[l] + dtv[eh] * (CS0 * f[l] + CS2 * k3[l] + CS3 * k4v[l] + CS4 * k5[l] + CS5 * k6[l]);
    drift(y1v, k7);

    float rs[GE] = {0.f, 0.f};
#pragma unroll
    for (int l = 0; l < 2; ++l) {
      const float yerr = dtv[eh] * (CE0 * f[l] + CE2 * k3[l] + CE3 * k4v[l] + CE4 * k5[l] + CE5 * k6[l] + CE6 * k7[l]);
      const float tol = ATOL_C + RTOL_C * fmaxf(fabsf(y[l]), fabsf(y1v[l]));
      const float r = yerr / tol;
      rs[eh] += r * r;
    }
    float rsum[GE];
    blocksum(rs, rsum);

    bool acc[GE];
#pragma unroll
    for (int g = 0; g < GE; ++g)
      acc[g] = act[g] && (sqrtf(rsum[g] * (1.0f / Hd)) <= 1.0f);

    if (acc[eh]) {
#pragma unroll
      for (int l = 0; l < 2; ++l) {
        ym[l] = y[l] + dtv[eh] * (CM0 * f[l] + CM2 * k3[l] + CM3 * k4v[l] + CM4 * k5[l] + CM5 * k6[l] + CM6 * k7[l]);
        py[l] = y[l]; pf[l] = f[l];
        y[l] = y1v[l]; f[l] = k7[l];
      }
    }
#pragma unroll
    for (int g = 0; g < GE; ++g) {
      if (!act[g]) continue;
      const float er = sqrtf(rsum[g] * (1.0f / Hd));
      if (acc[g]) {
        ptv[g] = tcur[g]; pdt[g] = dtv[g];
        tcur[g] = tcur[g] + dtv[g];
      }
      float dtn;
      if (er == 0.0f) {
        dtn = dtv[g] * 10.0f;
      } else {
        const float dfac = (er < 1.0f) ? 1.0f : 0.2f;
        const float fac = fminf(10.0f, fmaxf(0.9f * powf(er, -0.2f), dfac));
        dtn = dtv[g] * fac;
      }
      dtv[g] = fmaxf(dtn, 0.0f);
      act[g] = (tcur[g] < tfin[g]) && (dtv[g] > 0.0f);
    }
  }

  // ---- interpolate at t_final (4th-order fit) and fused FC ----
  const float fcwA = fcW[jj];
  const float fcwB = fcW[j1];
  float s[GE] = {0.f, 0.f};
#pragma unroll
  for (int l = 0; l < 2; ++l) {
    const float denom = tcur[eh] - ptv[eh];
    const float xr = (tfin[eh] - ptv[eh]) / denom;
    const float dy0 = pdt[eh] * pf[l];
    const float dy1 = pdt[eh] * f[l];
    const float aa = -2.f * dy0 + 2.f * dy1 - 8.f * py[l] - 8.f * y[l] + 16.f * ym[l];
    const float bb =  5.f * dy0 - 3.f * dy1 + 18.f * py[l] + 14.f * y[l] - 32.f * ym[l];
    const float cc = -4.f * dy0 + 1.f * dy1 - 11.f * py[l] - 5.f * y[l] + 16.f * ym[l];
    const float dd = dy0;
    const float ee = py[l];
    const float yf = (((aa * xr + bb) * xr + cc) * xr + dd) * xr + ee;
    s[eh] += yf * ((l == 1) ? fcwB : fcwA);
  }
  float ssum[GE];
  blocksum(s, ssum);
  if (tid == 0) {
#pragma unroll
    for (int g = 0; g < GE; ++g) {
      float o = ssum[g] + fcb[0];
#pragma unroll
      for (int m = 0; m < MET; ++m) o += meta[(bg0 + g) * MET + m] * fcW[Hd + m];
      outp[bg0 + g] = o;
    }
  }
}

// ---------------- host launcher ----------------
extern "C" void kernel_launch(void* const* d_in, const int* in_sizes, int n_in,
                              void* d_out, int out_size, void* d_ws, size_t ws_size,
                              hipStream_t stream)
{
  (void)in_sizes; (void)n_in; (void)out_size; (void)ws_size;

  const float* x    = (const float*)d_in[0];
  const float* meta = (const float*)d_in[1];
  const float* eps  = (const float*)d_in[2];
  const float* gWih = (const float*)d_in[3];
  const float* gWhh = (const float*)d_in[4];
  const float* gbih = (const float*)d_in[5];
  const float* gbhh = (const float*)d_in[6];
  const float* eW1  = (const float*)d_in[7];
  const float* eb1  = (const float*)d_in[8];
  const float* eW2  = (const float*)d_in[9];
  const float* eb2  = (const float*)d_in[10];
  const float* oW1  = (const float*)d_in[11];
  const float* ob1  = (const float*)d_in[12];
  const float* oW2  = (const float*)d_in[13];
  const float* ob2  = (const float*)d_in[14];
  const float* fcW  = (const float*)d_in[15];
  const float* fcb  = (const float*)d_in[16];
  float* out = (float*)d_out;
  float* ws  = (float*)d_ws;

  // ws layout (floats)
  float* WhhP = ws + 0;          //  786432
  float* WihT = ws + 786432;     //   12288
  float* eW1P = ws + 798720;     //  262144
  float* eW2P = ws + 1060864;    //  524288
  float* oW1P = ws + 1585152;    //  262144
  float* oW2P = ws + 1847296;    //  262144
  float* hA   = ws + 2109440;    //  262144 (h ping / z0)
  float* hB   = ws + 2371584;    //  262144 (h pong / o1)

  pack_kT4<<<(H3d * Hd + 255) / 256, 256, 0, stream>>>(gWhh, WhhP, H3d, Hd);
  transpose_k<<<(H3d * 8 + 255) / 256, 256, 0, stream>>>(gWih, WihT, H3d, 8);
  pack_kT4<<<(Hd * Hd + 255) / 256, 256, 0, stream>>>(eW1, eW1P, Hd, Hd);
  pack_kT4<<<(1024 * Hd + 255) / 256, 256, 0, stream>>>(eW2, eW2P, 1024, Hd);
  pack_kT4<<<(Hd * Hd + 255) / 256, 256, 0, stream>>>(oW1, oW1P, Hd, Hd);
  pack_kT4<<<(Hd * Hd + 255) / 256, 256, 0, stream>>>(oW2, oW2P, Hd, Hd);
  hipMemsetAsync(hA, 0, (size_t)Bsz * Hd * sizeof(float), stream);

  // persistent cooperative GRU: all 64 steps, grid-synced
  {
    void* args[] = { (void*)&x, (void*)&meta, (void*)&WihT, (void*)&WhhP,
                     (void*)&gbih, (void*)&gbhh, (void*)&hA, (void*)&hB };
    hipLaunchCooperativeKernel((const void*)gru_coop_kernel,
                               dim3(256), dim3(512), args, 0, stream);
  }
  // final h in hA (t=63 writes hA)
  dim3 egrid(32, 8);
  gemm_relu_kernel<<<egrid, 256, 0, stream>>>(hA, eW1P, eb1, hB);           // o1 -> hB
  enc2_z0_kernel<<<egrid, 256, 0, stream>>>(hB, eW2P, eb2, eps, hA);        // z0 -> hA
  ode_fc_kernel<<<Bsz / 2, 512, 0, stream>>>(x, meta, hA, oW1P, ob1, oW2P, ob2, fcW, fcb, out);
}

// Round 5
// 5044.670 us; speedup vs baseline: 1.2061x; 1.0527x over previous
//
#include <hip/hip_runtime.h>
#include <math.h>

// Problem dims
constexpr int Bsz  = 512;
constexpr int Nseq = 64;
constexpr int DX   = 4;
constexpr int MET  = 4;
constexpr int Hd   = 512;
constexpr int H3d  = 1536;

constexpr float RTOL_C = 1e-3f;
constexpr float ATOL_C = 1e-5f;

// ---- Dopri5 tableau (exactly as in jax.experimental.ode, f64->f32) ----
constexpr float SB10 = (float)(1.0/5.0);
constexpr float SB20 = (float)(3.0/40.0),  SB21 = (float)(9.0/40.0);
constexpr float SB30 = (float)(44.0/45.0), SB31 = (float)(-56.0/15.0), SB32 = (float)(32.0/9.0);
constexpr float SB40 = (float)(19372.0/6561.0), SB41 = (float)(-25360.0/2187.0),
                SB42 = (float)(64448.0/6561.0), SB43 = (float)(-212.0/729.0);
constexpr float SB50 = (float)(9017.0/3168.0),  SB51 = (float)(-355.0/33.0),
                SB52 = (float)(46732.0/5247.0), SB53 = (float)(49.0/176.0),
                SB54 = (float)(-5103.0/18656.0);
constexpr float CS0 = (float)(35.0/384.0), CS2 = (float)(500.0/1113.0),
                CS3 = (float)(125.0/192.0), CS4 = (float)(-2187.0/6784.0),
                CS5 = (float)(11.0/84.0);
// Shampine error coefficients (c_sol - c_star), as written in jax ode.py
constexpr float CE0 = (float)(35.0/384.0 - 1951.0/21600.0);
constexpr float CE2 = (float)(500.0/1113.0 - 22642.0/50085.0);
constexpr float CE3 = (float)(125.0/192.0 - 451.0/720.0);
constexpr float CE4 = (float)(-2187.0/6784.0 + 12231.0/42400.0);
constexpr float CE5 = (float)(11.0/84.0 - 649.0/6300.0);
constexpr float CE6 = (float)(-1.0/60.0);
// dps_c_mid for interpolation fit
constexpr float CM0 = (float)(6025192743.0/30085553152.0/2.0);
constexpr float CM2 = (float)(51252292925.0/65400821598.0/2.0);
constexpr float CM3 = (float)(-2691868925.0/45128329728.0/2.0);
constexpr float CM4 = (float)(187940372067.0/1594534317056.0/2.0);
constexpr float CM5 = (float)(-1776094331.0/19743644256.0/2.0);
constexpr float CM6 = (float)(11237099.0/235043384.0/2.0);

__device__ __forceinline__ float selu_f(float v) {
  const float scl = 1.0507009873554805f;
  const float alp = 1.6732632423543772f;
  float e = v > 0.f ? v : alp * expm1f(v);
  return scl * e;
}
__device__ __forceinline__ float sigmoid_f(float v) {
  return 1.f / (1.f + expf(-v));
}

// ---------------- weight repack kernels ----------------
// W: (R,K) row-major -> P[k/4][R][4] so inner k-loop uses one float4/row
__global__ void pack_kT4(const float* __restrict__ W, float* __restrict__ P, int R, int K) {
  int i = blockIdx.x * 256 + threadIdx.x;
  if (i >= R * K) return;
  int r = i / K, k = i % K;
  P[(k >> 2) * (R * 4) + r * 4 + (k & 3)] = W[i];
}
// plain transpose (R,C) -> (C,R)
__global__ void transpose_k(const float* __restrict__ W, float* __restrict__ T, int R, int C) {
  int i = blockIdx.x * 256 + threadIdx.x;
  if (i >= R * C) return;
  int r = i / C, c = i % C;
  T[c * R + r] = W[i];
}

// ---------------- persistent LDS-resident GRU (no global sync) ----------------
// 128 blocks x 512 threads. Block owns 4 batch rows x ALL 512 hidden units ->
// the whole 64-step recurrence is block-local (h lives in LDS; only
// __syncthreads between steps). R4 showed grid.sync costs ~55us/step; this
// removes it entirely. Weights (3MB) stream from L2 each step: 16 blocks/XCD
// x 3MB = 48MB/step/XCD / ~4.6TB/s ~= 10.4us/step ~= the 10.2us VALU floor.
// Thread j computes h[b][j] for its block's 4 rows; per-(b,j) accumulation
// order identical to previous rounds -> bit-identical h.
__global__ __launch_bounds__(512) void gru_lds_kernel(
    const float* __restrict__ x, const float* __restrict__ meta,
    const float* __restrict__ WihT, const float* __restrict__ WhhP,
    const float* __restrict__ bih, const float* __restrict__ bhh,
    float* __restrict__ hout)
{
  __shared__ __align__(16) float hs[4][Hd];          // 8 KB, resident h
  __shared__ __align__(16) float xs[4][Nseq * DX];   // 4 KB, staged x rows
  const int tid = threadIdx.x;
  const int j   = tid;                               // 0..511
  const int b0  = blockIdx.x * 4;

  // stage the 4 x-rows (256 floats each) into LDS
  for (int i = tid; i < 4 * Nseq; i += 512)
    *(float4*)&xs[i >> 6][(i & 63) * 4] =
        *(const float4*)&x[(b0 + (i >> 6)) * (Nseq * DX) + (i & 63) * 4];
  // h0 = 0
#pragma unroll
  for (int m = 0; m < 4; ++m) hs[m][j] = 0.f;

  // cache input-projection weights + biases for this j
  float wir[8], wiz[8], win[8];
#pragma unroll
  for (int kk = 0; kk < 8; ++kk) {
    wir[kk] = WihT[kk * H3d + j];
    wiz[kk] = WihT[kk * H3d + 512 + j];
    win[kk] = WihT[kk * H3d + 1024 + j];
  }
  const float bihr = bih[j], bihz = bih[512 + j], bihn = bih[1024 + j];
  const float bhhr = bhh[j], bhhz = bhh[512 + j], bhhn = bhh[1024 + j];
  float4 mv[4];
#pragma unroll
  for (int m = 0; m < 4; ++m) mv[m] = *(const float4*)&meta[(b0 + m) * MET];

  __syncthreads();

  for (int t = 0; t < Nseq; ++t) {
    float ar[4] = {0.f, 0.f, 0.f, 0.f};
    float az[4] = {0.f, 0.f, 0.f, 0.f};
    float an[4] = {0.f, 0.f, 0.f, 0.f};
#pragma unroll 4
    for (int k4 = 0; k4 < Hd / 4; ++k4) {
      const float4 wr = *(const float4*)&WhhP[(k4 * H3d + j) * 4];
      const float4 wz = *(const float4*)&WhhP[(k4 * H3d + 512 + j) * 4];
      const float4 wn = *(const float4*)&WhhP[(k4 * H3d + 1024 + j) * 4];
#pragma unroll
      for (int m = 0; m < 4; ++m) {
        const float4 hv = *(const float4*)&hs[m][k4 * 4];   // broadcast read
        ar[m] += wr.x * hv.x + wr.y * hv.y + wr.z * hv.z + wr.w * hv.w;
        az[m] += wz.x * hv.x + wz.y * hv.y + wz.z * hv.z + wz.w * hv.w;
        an[m] += wn.x * hv.x + wn.y * hv.y + wn.z * hv.z + wn.w * hv.w;
      }
    }

    float hnew[4];
#pragma unroll
    for (int m = 0; m < 4; ++m) {
      const float4 xv = *(const float4*)&xs[m][t * 4];
      float xm[8] = { xv.x, xv.y, xv.z, xv.w, mv[m].x, mv[m].y, mv[m].z, mv[m].w };
      float gr = bihr, gz = bihz, gn = bihn;
#pragma unroll
      for (int kk = 0; kk < 8; ++kk) {
        gr += xm[kk] * wir[kk];
        gz += xm[kk] * wiz[kk];
        gn += xm[kk] * win[kk];
      }
      const float ghr = ar[m] + bhhr;
      const float ghz = az[m] + bhhz;
      const float ghn = an[m] + bhhn;
      const float r = sigmoid_f(gr + ghr);
      const float z = sigmoid_f(gz + ghz);
      const float n = tanhf(gn + r * ghn);
      const float hold = hs[m][j];
      hnew[m] = (1.f - z) * n + z * hold;
    }
    __syncthreads();               // all reads of h[t] done
#pragma unroll
    for (int m = 0; m < 4; ++m) hs[m][j] = hnew[m];
    __syncthreads();               // h[t+1] visible
  }

#pragma unroll
  for (int m = 0; m < 4; ++m) hout[(b0 + m) * Hd + j] = hs[m][j];
}

// ---------------- encoder layer 1: relu(A @ W^T + b) ----------------
__global__ __launch_bounds__(256) void gemm_relu_kernel(
    const float* __restrict__ A, const float* __restrict__ WP,
    const float* __restrict__ bias, float* __restrict__ Cout)
{
  __shared__ __align__(16) float as[16 * Hd];
  const int tid  = threadIdx.x;
  const int jl   = tid & 63;
  const int bsub = tid >> 6;
  const int j    = blockIdx.y * 64 + jl;
  const int b0   = blockIdx.x * 16;

  for (int i = tid; i < 16 * Hd; i += 256) as[i] = A[b0 * Hd + i];
  __syncthreads();

  float acc[4] = {0.f, 0.f, 0.f, 0.f};
#pragma unroll 2
  for (int k4 = 0; k4 < Hd / 4; ++k4) {
    const float4 w = *(const float4*)&WP[(k4 * Hd + j) * 4];
#pragma unroll
    for (int m = 0; m < 4; ++m) {
      const float4 av = *(const float4*)&as[(bsub * 4 + m) * Hd + k4 * 4];
      acc[m] += w.x * av.x + w.y * av.y + w.z * av.z + w.w * av.w;
    }
  }
  const float bj = bias[j];
#pragma unroll
  for (int m = 0; m < 4; ++m) {
    const int b = b0 + bsub * 4 + m;
    float v = acc[m] + bj;
    Cout[b * Hd + j] = v > 0.f ? v : 0.f;
  }
}

// ---------------- encoder layer 2 + reparam: z0 = eps*std + mean ----------------
__global__ __launch_bounds__(256) void enc2_z0_kernel(
    const float* __restrict__ O1, const float* __restrict__ W2P,  // [k4][1024][4]
    const float* __restrict__ b2, const float* __restrict__ eps,
    float* __restrict__ z0)
{
  __shared__ __align__(16) float as[16 * Hd];
  const int tid  = threadIdx.x;
  const int jl   = tid & 63;
  const int bsub = tid >> 6;
  const int j    = blockIdx.y * 64 + jl;
  const int b0   = blockIdx.x * 16;

  for (int i = tid; i < 16 * Hd; i += 256) as[i] = O1[b0 * Hd + i];
  __syncthreads();

  float am[4] = {0.f, 0.f, 0.f, 0.f};
  float asd[4] = {0.f, 0.f, 0.f, 0.f};
#pragma unroll 2
  for (int k4 = 0; k4 < Hd / 4; ++k4) {
    const float4 wm = *(const float4*)&W2P[(k4 * 1024 + j) * 4];
    const float4 ws = *(const float4*)&W2P[(k4 * 1024 + 512 + j) * 4];
#pragma unroll
    for (int m = 0; m < 4; ++m) {
      const float4 av = *(const float4*)&as[(bsub * 4 + m) * Hd + k4 * 4];
      am[m]  += wm.x * av.x + wm.y * av.y + wm.z * av.z + wm.w * av.w;
      asd[m] += ws.x * av.x + ws.y * av.y + ws.z * av.z + ws.w * av.w;
    }
  }
  const float bm = b2[j], bs = b2[512 + j];
#pragma unroll
  for (int m = 0; m < 4; ++m) {
    const int b = b0 + bsub * 4 + m;
    const float mean = am[m] + bm;
    const float sd   = asd[m] + bs;
    z0[b * Hd + j] = eps[b * Hd + j] * sd + mean;
  }
}

// ---------------- adaptive Dopri5 ODE solve + final FC ----------------
// 256 blocks x 512 threads, GE=2 elements per block (all 256 CUs active).
// Thread (jj = tid&255, eh = tid>>8): owns outputs j in {jj, jj+256} for
// element eh. zsh is [e][k] so the k-loop reads one broadcast ds_read_b128
// per 8 FMA. Per-(j,e) k-accumulation order identical to previous rounds ->
// bit-identical trajectories. Control state for BOTH elements is replicated
// in every thread (derived from block-uniform reductions only).
__global__ __launch_bounds__(512) void ode_fc_kernel(
    const float* __restrict__ x, const float* __restrict__ meta,
    const float* __restrict__ z0in,
    const float* __restrict__ W1P, const float* __restrict__ b1v,
    const float* __restrict__ W2P, const float* __restrict__ b2v,
    const float* __restrict__ fcW, const float* __restrict__ fcb,
    float* __restrict__ outp)
{
  constexpr int GE = 2;
  __shared__ __align__(16) float zsh[GE][Hd];   // 4 KB
  __shared__ float red[8 * GE];
  const int tid = threadIdx.x;
  const int jj  = tid & 255;
  const int eh  = tid >> 8;            // element 0/1 (wave-uniform)
  const int j1  = jj + 256;
  const int bg0 = blockIdx.x * GE;

  const float b1a = b1v[jj], b1b = b1v[j1];
  const float b2a = b2v[jj], b2b = b2v[j1];

  // drift for the thread's 2 (j, eh) slots
  auto drift = [&](const float (&in)[2], float (&out)[2]) {
    __syncthreads();
    zsh[eh][jj] = in[0];
    zsh[eh][j1] = in[1];
    __syncthreads();
    float u0 = b1a, u1 = b1b;
#pragma unroll 4
    for (int k4 = 0; k4 < Hd / 4; ++k4) {
      const float4 wA = *(const float4*)&W1P[(k4 * Hd + jj) * 4];
      const float4 wB = *(const float4*)&W1P[(k4 * Hd + j1) * 4];
      const float4 z  = *(const float4*)&zsh[eh][k4 * 4];
      u0 += wA.x * z.x + wA.y * z.y + wA.z * z.z + wA.w * z.w;
      u1 += wB.x * z.x + wB.y * z.y + wB.z * z.z + wB.w * z.w;
    }
    u0 = selu_f(u0); u1 = selu_f(u1);
    __syncthreads();
    zsh[eh][jj] = u0;
    zsh[eh][j1] = u1;
    __syncthreads();
    float v0 = b2a, v1 = b2b;
#pragma unroll 4
    for (int k4 = 0; k4 < Hd / 4; ++k4) {
      const float4 wA = *(const float4*)&W2P[(k4 * Hd + jj) * 4];
      const float4 wB = *(const float4*)&W2P[(k4 * Hd + j1) * 4];
      const float4 z  = *(const float4*)&zsh[eh][k4 * 4];
      v0 += wA.x * z.x + wA.y * z.y + wA.z * z.z + wA.w * z.w;
      v1 += wB.x * z.x + wB.y * z.y + wB.z * z.z + wB.w * z.w;
    }
    out[0] = v0; out[1] = v1;
  };

  // block-wide per-element sum; all threads receive identical results
  auto blocksum = [&](float (&v)[GE], float (&s)[GE]) {
#pragma unroll
    for (int off = 32; off > 0; off >>= 1) {
#pragma unroll
      for (int g = 0; g < GE; ++g) v[g] += __shfl_down(v[g], off);
    }
    __syncthreads();
    if ((tid & 63) == 0) {
      const int w = tid >> 6;
#pragma unroll
      for (int g = 0; g < GE; ++g) red[w * GE + g] = v[g];
    }
    __syncthreads();
#pragma unroll
    for (int g = 0; g < GE; ++g) {
      float t = 0.f;
#pragma unroll
      for (int w = 0; w < 8; ++w) t += red[w * GE + g];
      s[g] = t;
    }
  };

  float y[2], f[2], py[2], pf[2], ym[2];
  float tcur[GE], dtv[GE], tfin[GE], ptv[GE], pdt[GE];
  bool act[GE];

  y[0] = z0in[(bg0 + eh) * Hd + jj];
  y[1] = z0in[(bg0 + eh) * Hd + j1];
#pragma unroll
  for (int g = 0; g < GE; ++g) {
    tcur[g] = x[((bg0 + g) * Nseq + 0) * DX];
    tfin[g] = x[((bg0 + g) * Nseq + (Nseq - 1)) * DX];
  }

  drift(y, f);

  // ---- initial step size (Hairer / jax variant) ----
  float sc[2];
  float q0[GE] = {0.f, 0.f}, q1[GE] = {0.f, 0.f};
#pragma unroll
  for (int l = 0; l < 2; ++l) {
    sc[l] = ATOL_C + RTOL_C * fabsf(y[l]);
    const float a = y[l] / sc[l], b = f[l] / sc[l];
    q0[eh] += a * a;
    q1[eh] += b * b;
  }
  float d0s[GE], d1s[GE];
  blocksum(q0, d0s);
  blocksum(q1, d1s);
  float h0[GE];
#pragma unroll
  for (int g = 0; g < GE; ++g) {
    const float d0 = sqrtf(d0s[g]), d1 = sqrtf(d1s[g]);
    h0[g] = (d0 < 1e-5f || d1 < 1e-5f) ? 1e-6f : 0.01f * d0 / d1;
  }
  float yin[2], f1h[2];
#pragma unroll
  for (int l = 0; l < 2; ++l) yin[l] = y[l] + h0[eh] * f[l];
  drift(yin, f1h);
  float q2[GE] = {0.f, 0.f};
#pragma unroll
  for (int l = 0; l < 2; ++l) {
    const float dd = (f1h[l] - f[l]) / sc[l];
    q2[eh] += dd * dd;
  }
  float d2s[GE];
  blocksum(q2, d2s);
#pragma unroll
  for (int g = 0; g < GE; ++g) {
    const float d1 = sqrtf(d1s[g]);
    const float d2 = sqrtf(d2s[g]) / h0[g];
    const float h1 = (d1 <= 1e-15f && d2 <= 1e-15f)
                 ? fmaxf(1e-6f, h0[g] * 1e-3f)
                 : powf(0.01f / (d1 + d2), 0.2f);   // jax uses d1+d2 here
    dtv[g] = fminf(100.f * h0[g], h1);
    ptv[g] = tcur[g]; pdt[g] = dtv[g];
    act[g] = (tcur[g] < tfin[g]) && (dtv[g] > 0.f);
  }
#pragma unroll
  for (int l = 0; l < 2; ++l) { py[l] = y[l]; pf[l] = f[l]; ym[l] = y[l]; }

  // ---- adaptive stepping loop ----
  float k2[2], k3[2], k4v[2], k5[2], k6[2], k7[2], y1v[2];
  for (int iter = 0; iter < 4000; ++iter) {
    if (!(act[0] || act[1])) break;

#pragma unroll
    for (int l = 0; l < 2; ++l) yin[l] = y[l] + dtv[eh] * (SB10 * f[l]);
    drift(yin, k2);

#pragma unroll
    for (int l = 0; l < 2; ++l)
      yin[l] = y[l] + dtv[eh] * (SB20 * f[l] + SB21 * k2[l]);
    drift(yin, k3);

#pragma unroll
    for (int l = 0; l < 2; ++l)
      yin[l] = y[l] + dtv[eh] * (SB30 * f[l] + SB31 * k2[l] + SB32 * k3[l]);
    drift(yin, k4v);

#pragma unroll
    for (int l = 0; l < 2; ++l)
      yin[l] = y[l] + dtv[eh] * (SB40 * f[l] + SB41 * k2[l] + SB42 * k3[l] + SB43 * k4v[l]);
    drift(yin, k5);

#pragma unroll
    for (int l = 0; l < 2; ++l)
      yin[l] = y[l] + dtv[eh] * (SB50 * f[l] + SB51 * k2[l] + SB52 * k3[l] + SB53 * k4v[l] + SB54 * k5[l]);
    drift(yin, k6);

#pragma unroll
    for (int l = 0; l < 2; ++l)
      y1v[l] = y[l] + dtv[eh] * (CS0 * f[l] + CS2 * k3[l] + CS3 * k4v[l] + CS4 * k5[l] + CS5 * k6[l]);
    drift(y1v, k7);

    float rs[GE] = {0.f, 0.f};
#pragma unroll
    for (int l = 0; l < 2; ++l) {
      const float yerr = dtv[eh] * (CE0 * f[l] + CE2 * k3[l] + CE3 * k4v[l] + CE4 * k5[l] + CE5 * k6[l] + CE6 * k7[l]);
      const float tol = ATOL_C + RTOL_C * fmaxf(fabsf(y[l]), fabsf(y1v[l]));
      const float r = yerr / tol;
      rs[eh] += r * r;
    }
    float rsum[GE];
    blocksum(rs, rsum);

    bool acc[GE];
#pragma unroll
    for (int g = 0; g < GE; ++g)
      acc[g] = act[g] && (sqrtf(rsum[g] * (1.0f / Hd)) <= 1.0f);

    if (acc[eh]) {
#pragma unroll
      for (int l = 0; l < 2; ++l) {
        ym[l] = y[l] + dtv[eh] * (CM0 * f[l] + CM2 * k3[l] + CM3 * k4v[l] + CM4 * k5[l] + CM5 * k6[l] + CM6 * k7[l]);
        py[l] = y[l]; pf[l] = f[l];
        y[l] = y1v[l]; f[l] = k7[l];
      }
    }
#pragma unroll
    for (int g = 0; g < GE; ++g) {
      if (!act[g]) continue;
      const float er = sqrtf(rsum[g] * (1.0f / Hd));
      if (acc[g]) {
        ptv[g] = tcur[g]; pdt[g] = dtv[g];
        tcur[g] = tcur[g] + dtv[g];
      }
      float dtn;
      if (er == 0.0f) {
        dtn = dtv[g] * 10.0f;
      } else {
        const float dfac = (er < 1.0f) ? 1.0f : 0.2f;
        const float fac = fminf(10.0f, fmaxf(0.9f * powf(er, -0.2f), dfac));
        dtn = dtv[g] * fac;
      }
      dtv[g] = fmaxf(dtn, 0.0f);
      act[g] = (tcur[g] < tfin[g]) && (dtv[g] > 0.0f);
    }
  }

  // ---- interpolate at t_final (4th-order fit) and fused FC ----
  const float fcwA = fcW[jj];
  const float fcwB = fcW[j1];
  float s[GE] = {0.f, 0.f};
#pragma unroll
  for (int l = 0; l < 2; ++l) {
    const float denom = tcur[eh] - ptv[eh];
    const float xr = (tfin[eh] - ptv[eh]) / denom;
    const float dy0 = pdt[eh] * pf[l];
    const float dy1 = pdt[eh] * f[l];
    const float aa = -2.f * dy0 + 2.f * dy1 - 8.f * py[l] - 8.f * y[l] + 16.f * ym[l];
    const float bb =  5.f * dy0 - 3.f * dy1 + 18.f * py[l] + 14.f * y[l] - 32.f * ym[l];
    const float cc = -4.f * dy0 + 1.f * dy1 - 11.f * py[l] - 5.f * y[l] + 16.f * ym[l];
    const float dd = dy0;
    const float ee = py[l];
    const float yf = (((aa * xr + bb) * xr + cc) * xr + dd) * xr + ee;
    s[eh] += yf * ((l == 1) ? fcwB : fcwA);
  }
  float ssum[GE];
  blocksum(s, ssum);
  if (tid == 0) {
#pragma unroll
    for (int g = 0; g < GE; ++g) {
      float o = ssum[g] + fcb[0];
#pragma unroll
      for (int m = 0; m < MET; ++m) o += meta[(bg0 + g) * MET + m] * fcW[Hd + m];
      outp[bg0 + g] = o;
    }
  }
}

// ---------------- host launcher ----------------
extern "C" void kernel_launch(void* const* d_in, const int* in_sizes, int n_in,
                              void* d_out, int out_size, void* d_ws, size_t ws_size,
                              hipStream_t stream)
{
  (void)in_sizes; (void)n_in; (void)out_size; (void)ws_size;

  const float* x    = (const float*)d_in[0];
  const float* meta = (const float*)d_in[1];
  const float* eps  = (const float*)d_in[2];
  const float* gWih = (const float*)d_in[3];
  const float* gWhh = (const float*)d_in[4];
  const float* gbih = (const float*)d_in[5];
  const float* gbhh = (const float*)d_in[6];
  const float* eW1  = (const float*)d_in[7];
  const float* eb1  = (const float*)d_in[8];
  const float* eW2  = (const float*)d_in[9];
  const float* eb2  = (const float*)d_in[10];
  const float* oW1  = (const float*)d_in[11];
  const float* ob1  = (const float*)d_in[12];
  const float* oW2  = (const float*)d_in[13];
  const float* ob2  = (const float*)d_in[14];
  const float* fcW  = (const float*)d_in[15];
  const float* fcb  = (const float*)d_in[16];
  float* out = (float*)d_out;
  float* ws  = (float*)d_ws;

  // ws layout (floats)
  float* WhhP = ws + 0;          //  786432
  float* WihT = ws + 786432;     //   12288
  float* eW1P = ws + 798720;     //  262144
  float* eW2P = ws + 1060864;    //  524288
  float* oW1P = ws + 1585152;    //  262144
  float* oW2P = ws + 1847296;    //  262144
  float* hA   = ws + 2109440;    //  262144 (final h / z0)
  float* hB   = ws + 2371584;    //  262144 (o1)

  pack_kT4<<<(H3d * Hd + 255) / 256, 256, 0, stream>>>(gWhh, WhhP, H3d, Hd);
  transpose_k<<<(H3d * 8 + 255) / 256, 256, 0, stream>>>(gWih, WihT, H3d, 8);
  pack_kT4<<<(Hd * Hd + 255) / 256, 256, 0, stream>>>(eW1, eW1P, Hd, Hd);
  pack_kT4<<<(1024 * Hd + 255) / 256, 256, 0, stream>>>(eW2, eW2P, 1024, Hd);
  pack_kT4<<<(Hd * Hd + 255) / 256, 256, 0, stream>>>(oW1, oW1P, Hd, Hd);
  pack_kT4<<<(Hd * Hd + 255) / 256, 256, 0, stream>>>(oW2, oW2P, Hd, Hd);

  // single-launch GRU: h resident in LDS, no global sync
  gru_lds_kernel<<<Bsz / 4, 512, 0, stream>>>(x, meta, WihT, WhhP, gbih, gbhh, hA);

  // encoder + reparam
  dim3 egrid(32, 8);
  gemm_relu_kernel<<<egrid, 256, 0, stream>>>(hA, eW1P, eb1, hB);           // o1 -> hB
  enc2_z0_kernel<<<egrid, 256, 0, stream>>>(hB, eW2P, eb2, eps, hA);        // z0 -> hA
  ode_fc_kernel<<<Bsz / 2, 512, 0, stream>>>(x, meta, hA, oW1P, ob1, oW2P, ob2, fcW, fcb, out);
}

// Round 6
// 2893.757 us; speedup vs baseline: 2.1026x; 1.7433x over previous
//
#include <hip/hip_runtime.h>
#include <math.h>

// Problem dims
constexpr int Bsz  = 512;
constexpr int Nseq = 64;
constexpr int DX   = 4;
constexpr int MET  = 4;
constexpr int Hd   = 512;
constexpr int H3d  = 1536;

constexpr float RTOL_C = 1e-3f;
constexpr float ATOL_C = 1e-5f;

// ---- Dopri5 tableau (exactly as in jax.experimental.ode, f64->f32) ----
constexpr float SB10 = (float)(1.0/5.0);
constexpr float SB20 = (float)(3.0/40.0),  SB21 = (float)(9.0/40.0);
constexpr float SB30 = (float)(44.0/45.0), SB31 = (float)(-56.0/15.0), SB32 = (float)(32.0/9.0);
constexpr float SB40 = (float)(19372.0/6561.0), SB41 = (float)(-25360.0/2187.0),
                SB42 = (float)(64448.0/6561.0), SB43 = (float)(-212.0/729.0);
constexpr float SB50 = (float)(9017.0/3168.0),  SB51 = (float)(-355.0/33.0),
                SB52 = (float)(46732.0/5247.0), SB53 = (float)(49.0/176.0),
                SB54 = (float)(-5103.0/18656.0);
constexpr float CS0 = (float)(35.0/384.0), CS2 = (float)(500.0/1113.0),
                CS3 = (float)(125.0/192.0), CS4 = (float)(-2187.0/6784.0),
                CS5 = (float)(11.0/84.0);
// Shampine error coefficients (c_sol - c_star), as written in jax ode.py
constexpr float CE0 = (float)(35.0/384.0 - 1951.0/21600.0);
constexpr float CE2 = (float)(500.0/1113.0 - 22642.0/50085.0);
constexpr float CE3 = (float)(125.0/192.0 - 451.0/720.0);
constexpr float CE4 = (float)(-2187.0/6784.0 + 12231.0/42400.0);
constexpr float CE5 = (float)(11.0/84.0 - 649.0/6300.0);
constexpr float CE6 = (float)(-1.0/60.0);
// dps_c_mid for interpolation fit
constexpr float CM0 = (float)(6025192743.0/30085553152.0/2.0);
constexpr float CM2 = (float)(51252292925.0/65400821598.0/2.0);
constexpr float CM3 = (float)(-2691868925.0/45128329728.0/2.0);
constexpr float CM4 = (float)(187940372067.0/1594534317056.0/2.0);
constexpr float CM5 = (float)(-1776094331.0/19743644256.0/2.0);
constexpr float CM6 = (float)(11237099.0/235043384.0/2.0);

__device__ __forceinline__ float selu_f(float v) {
  const float scl = 1.0507009873554805f;
  const float alp = 1.6732632423543772f;
  float e = v > 0.f ? v : alp * expm1f(v);
  return scl * e;
}
__device__ __forceinline__ float sigmoid_f(float v) {
  return 1.f / (1.f + expf(-v));
}

// ---------------- weight repack kernels ----------------
// W: (R,K) row-major -> P[k/4][R][4] so inner k-loop uses one float4/row
__global__ void pack_kT4(const float* __restrict__ W, float* __restrict__ P, int R, int K) {
  int i = blockIdx.x * 256 + threadIdx.x;
  if (i >= R * K) return;
  int r = i / K, k = i % K;
  P[(k >> 2) * (R * 4) + r * 4 + (k & 3)] = W[i];
}
// plain transpose (R,C) -> (C,R)
__global__ void transpose_k(const float* __restrict__ W, float* __restrict__ T, int R, int C) {
  int i = blockIdx.x * 256 + threadIdx.x;
  if (i >= R * C) return;
  int r = i / C, c = i % C;
  T[c * R + r] = W[i];
}

// ---------------- GRU step: h_out = GRUCell(xm_t, h_in) ----------------
// grid (32,8) = 256 blocks (1/CU), 512 threads (8 waves/CU, 2/SIMD).
// Block tile: 16 batch rows x 64 hidden cols; wave rg owns rows 2rg, 2rg+1.
// Per-CU per-step traffic: 393KB weights + 32KB h ~= 2.8us L1; VALU 5.1us.
// (R4/R5 lesson: per-CU L1 stream is the wall; j-tiling keeps it at 0.4MB
//  vs 3MB for all-j-per-block designs. Per-step launch beats grid.sync.)
__global__ __launch_bounds__(512) void gru_step_kernel(
    const float* __restrict__ x, const float* __restrict__ meta,
    const float* __restrict__ WihT, const float* __restrict__ WhhP,
    const float* __restrict__ bih, const float* __restrict__ bhh,
    const float* __restrict__ h_in, float* __restrict__ h_out, int t)
{
  __shared__ __align__(16) float hs[16 * Hd];    // 32 KB h tile
  const int tid = threadIdx.x;
  const int jl  = tid & 63;
  const int rg  = tid >> 6;                      // wave 0..7 -> rows 2rg, 2rg+1
  const int j   = blockIdx.y * 64 + jl;
  const int b0  = blockIdx.x * 16;

  // stage this block's 16x512 h tile into LDS (coalesced float4)
  for (int i = tid; i < 16 * Hd / 4; i += 512)
    *(float4*)&hs[i * 4] = *(const float4*)&h_in[b0 * Hd + i * 4];
  __syncthreads();

  float ar0 = 0.f, az0 = 0.f, an0 = 0.f;
  float ar1 = 0.f, az1 = 0.f, an1 = 0.f;
#pragma unroll 4
  for (int k4 = 0; k4 < Hd / 4; ++k4) {
    const float4 wr = *(const float4*)&WhhP[(k4 * H3d + j) * 4];
    const float4 wz = *(const float4*)&WhhP[(k4 * H3d + 512 + j) * 4];
    const float4 wn = *(const float4*)&WhhP[(k4 * H3d + 1024 + j) * 4];
    const float4 h0 = *(const float4*)&hs[(rg * 2 + 0) * Hd + k4 * 4];  // broadcast
    const float4 h1 = *(const float4*)&hs[(rg * 2 + 1) * Hd + k4 * 4];
    ar0 += wr.x * h0.x + wr.y * h0.y + wr.z * h0.z + wr.w * h0.w;
    az0 += wz.x * h0.x + wz.y * h0.y + wz.z * h0.z + wz.w * h0.w;
    an0 += wn.x * h0.x + wn.y * h0.y + wn.z * h0.z + wn.w * h0.w;
    ar1 += wr.x * h1.x + wr.y * h1.y + wr.z * h1.z + wr.w * h1.w;
    az1 += wz.x * h1.x + wz.y * h1.y + wz.z * h1.z + wz.w * h1.w;
    an1 += wn.x * h1.x + wn.y * h1.y + wn.z * h1.z + wn.w * h1.w;
  }

  const float bihr = bih[j], bihz = bih[512 + j], bihn = bih[1024 + j];
  const float bhhr = bhh[j], bhhz = bhh[512 + j], bhhn = bhh[1024 + j];
  float wir[8], wiz[8], win[8];
#pragma unroll
  for (int kk = 0; kk < 8; ++kk) {
    wir[kk] = WihT[kk * H3d + j];
    wiz[kk] = WihT[kk * H3d + 512 + j];
    win[kk] = WihT[kk * H3d + 1024 + j];
  }

#pragma unroll
  for (int m = 0; m < 2; ++m) {
    const int bl = rg * 2 + m;
    const int b  = b0 + bl;
    const float4 xv = *(const float4*)&x[(b * Nseq + t) * DX];
    const float4 mv = *(const float4*)&meta[b * MET];
    float xm[8] = { xv.x, xv.y, xv.z, xv.w, mv.x, mv.y, mv.z, mv.w };
    float gr = bihr, gz = bihz, gn = bihn;
#pragma unroll
    for (int kk = 0; kk < 8; ++kk) {
      gr += xm[kk] * wir[kk];
      gz += xm[kk] * wiz[kk];
      gn += xm[kk] * win[kk];
    }
    const float ghr = (m ? ar1 : ar0) + bhhr;
    const float ghz = (m ? az1 : az0) + bhhz;
    const float ghn = (m ? an1 : an0) + bhhn;
    const float r = sigmoid_f(gr + ghr);
    const float z = sigmoid_f(gz + ghz);
    const float n = tanhf(gn + r * ghn);
    const float hold = hs[bl * Hd + j];
    h_out[b * Hd + j] = (1.f - z) * n + z * hold;
  }
}

// ---------------- encoder layer 1: relu(A @ W^T + b) ----------------
__global__ __launch_bounds__(256) void gemm_relu_kernel(
    const float* __restrict__ A, const float* __restrict__ WP,
    const float* __restrict__ bias, float* __restrict__ Cout)
{
  __shared__ __align__(16) float as[16 * Hd];
  const int tid  = threadIdx.x;
  const int jl   = tid & 63;
  const int bsub = tid >> 6;
  const int j    = blockIdx.y * 64 + jl;
  const int b0   = blockIdx.x * 16;

  for (int i = tid; i < 16 * Hd; i += 256) as[i] = A[b0 * Hd + i];
  __syncthreads();

  float acc[4] = {0.f, 0.f, 0.f, 0.f};
#pragma unroll 2
  for (int k4 = 0; k4 < Hd / 4; ++k4) {
    const float4 w = *(const float4*)&WP[(k4 * Hd + j) * 4];
#pragma unroll
    for (int m = 0; m < 4; ++m) {
      const float4 av = *(const float4*)&as[(bsub * 4 + m) * Hd + k4 * 4];
      acc[m] += w.x * av.x + w.y * av.y + w.z * av.z + w.w * av.w;
    }
  }
  const float bj = bias[j];
#pragma unroll
  for (int m = 0; m < 4; ++m) {
    const int b = b0 + bsub * 4 + m;
    float v = acc[m] + bj;
    Cout[b * Hd + j] = v > 0.f ? v : 0.f;
  }
}

// ---------------- encoder layer 2 + reparam: z0 = eps*std + mean ----------------
__global__ __launch_bounds__(256) void enc2_z0_kernel(
    const float* __restrict__ O1, const float* __restrict__ W2P,  // [k4][1024][4]
    const float* __restrict__ b2, const float* __restrict__ eps,
    float* __restrict__ z0)
{
  __shared__ __align__(16) float as[16 * Hd];
  const int tid  = threadIdx.x;
  const int jl   = tid & 63;
  const int bsub = tid >> 6;
  const int j    = blockIdx.y * 64 + jl;
  const int b0   = blockIdx.x * 16;

  for (int i = tid; i < 16 * Hd; i += 256) as[i] = O1[b0 * Hd + i];
  __syncthreads();

  float am[4] = {0.f, 0.f, 0.f, 0.f};
  float asd[4] = {0.f, 0.f, 0.f, 0.f};
#pragma unroll 2
  for (int k4 = 0; k4 < Hd / 4; ++k4) {
    const float4 wm = *(const float4*)&W2P[(k4 * 1024 + j) * 4];
    const float4 ws = *(const float4*)&W2P[(k4 * 1024 + 512 + j) * 4];
#pragma unroll
    for (int m = 0; m < 4; ++m) {
      const float4 av = *(const float4*)&as[(bsub * 4 + m) * Hd + k4 * 4];
      am[m]  += wm.x * av.x + wm.y * av.y + wm.z * av.z + wm.w * av.w;
      asd[m] += ws.x * av.x + ws.y * av.y + ws.z * av.z + ws.w * av.w;
    }
  }
  const float bm = b2[j], bs = b2[512 + j];
#pragma unroll
  for (int m = 0; m < 4; ++m) {
    const int b = b0 + bsub * 4 + m;
    const float mean = am[m] + bm;
    const float sd   = asd[m] + bs;
    z0[b * Hd + j] = eps[b * Hd + j] * sd + mean;
  }
}

// ---------------- adaptive Dopri5 ODE solve + final FC ----------------
// 256 blocks x 512 threads, GE=2 elements per block (all 256 CUs active).
// At the per-CU L1 traffic floor: each CU streams W1+W2 = 2MB per drift
// (~14us) regardless of GE -- leave structure as-is.
__global__ __launch_bounds__(512) void ode_fc_kernel(
    const float* __restrict__ x, const float* __restrict__ meta,
    const float* __restrict__ z0in,
    const float* __restrict__ W1P, const float* __restrict__ b1v,
    const float* __restrict__ W2P, const float* __restrict__ b2v,
    const float* __restrict__ fcW, const float* __restrict__ fcb,
    float* __restrict__ outp)
{
  constexpr int GE = 2;
  __shared__ __align__(16) float zsh[GE][Hd];   // 4 KB
  __shared__ float red[8 * GE];
  const int tid = threadIdx.x;
  const int jj  = tid & 255;
  const int eh  = tid >> 8;            // element 0/1 (wave-uniform)
  const int j1  = jj + 256;
  const int bg0 = blockIdx.x * GE;

  const float b1a = b1v[jj], b1b = b1v[j1];
  const float b2a = b2v[jj], b2b = b2v[j1];

  // drift for the thread's 2 (j, eh) slots
  auto drift = [&](const float (&in)[2], float (&out)[2]) {
    __syncthreads();
    zsh[eh][jj] = in[0];
    zsh[eh][j1] = in[1];
    __syncthreads();
    float u0 = b1a, u1 = b1b;
#pragma unroll 4
    for (int k4 = 0; k4 < Hd / 4; ++k4) {
      const float4 wA = *(const float4*)&W1P[(k4 * Hd + jj) * 4];
      const float4 wB = *(const float4*)&W1P[(k4 * Hd + j1) * 4];
      const float4 z  = *(const float4*)&zsh[eh][k4 * 4];
      u0 += wA.x * z.x + wA.y * z.y + wA.z * z.z + wA.w * z.w;
      u1 += wB.x * z.x + wB.y * z.y + wB.z * z.z + wB.w * z.w;
    }
    u0 = selu_f(u0); u1 = selu_f(u1);
    __syncthreads();
    zsh[eh][jj] = u0;
    zsh[eh][j1] = u1;
    __syncthreads();
    float v0 = b2a, v1 = b2b;
#pragma unroll 4
    for (int k4 = 0; k4 < Hd / 4; ++k4) {
      const float4 wA = *(const float4*)&W2P[(k4 * Hd + jj) * 4];
      const float4 wB = *(const float4*)&W2P[(k4 * Hd + j1) * 4];
      const float4 z  = *(const float4*)&zsh[eh][k4 * 4];
      v0 += wA.x * z.x + wA.y * z.y + wA.z * z.z + wA.w * z.w;
      v1 += wB.x * z.x + wB.y * z.y + wB.z * z.z + wB.w * z.w;
    }
    out[0] = v0; out[1] = v1;
  };

  // block-wide per-element sum; all threads receive identical results
  auto blocksum = [&](float (&v)[GE], float (&s)[GE]) {
#pragma unroll
    for (int off = 32; off > 0; off >>= 1) {
#pragma unroll
      for (int g = 0; g < GE; ++g) v[g] += __shfl_down(v[g], off);
    }
    __syncthreads();
    if ((tid & 63) == 0) {
      const int w = tid >> 6;
#pragma unroll
      for (int g = 0; g < GE; ++g) red[w * GE + g] = v[g];
    }
    __syncthreads();
#pragma unroll
    for (int g = 0; g < GE; ++g) {
      float t = 0.f;
#pragma unroll
      for (int w = 0; w < 8; ++w) t += red[w * GE + g];
      s[g] = t;
    }
  };

  float y[2], f[2], py[2], pf[2], ym[2];
  float tcur[GE], dtv[GE], tfin[GE], ptv[GE], pdt[GE];
  bool act[GE];

  y[0] = z0in[(bg0 + eh) * Hd + jj];
  y[1] = z0in[(bg0 + eh) * Hd + j1];
#pragma unroll
  for (int g = 0; g < GE; ++g) {
    tcur[g] = x[((bg0 + g) * Nseq + 0) * DX];
    tfin[g] = x[((bg0 + g) * Nseq + (Nseq - 1)) * DX];
  }

  drift(y, f);

  // ---- initial step size (Hairer / jax variant) ----
  float sc[2];
  float q0[GE] = {0.f, 0.f}, q1[GE] = {0.f, 0.f};
#pragma unroll
  for (int l = 0; l < 2; ++l) {
    sc[l] = ATOL_C + RTOL_C * fabsf(y[l]);
    const float a = y[l] / sc[l], b = f[l] / sc[l];
    q0[eh] += a * a;
    q1[eh] += b * b;
  }
  float d0s[GE], d1s[GE];
  blocksum(q0, d0s);
  blocksum(q1, d1s);
  float h0[GE];
#pragma unroll
  for (int g = 0; g < GE; ++g) {
    const float d0 = sqrtf(d0s[g]), d1 = sqrtf(d1s[g]);
    h0[g] = (d0 < 1e-5f || d1 < 1e-5f) ? 1e-6f : 0.01f * d0 / d1;
  }
  float yin[2], f1h[2];
#pragma unroll
  for (int l = 0; l < 2; ++l) yin[l] = y[l] + h0[eh] * f[l];
  drift(yin, f1h);
  float q2[GE] = {0.f, 0.f};
#pragma unroll
  for (int l = 0; l < 2; ++l) {
    const float dd = (f1h[l] - f[l]) / sc[l];
    q2[eh] += dd * dd;
  }
  float d2s[GE];
  blocksum(q2, d2s);
#pragma unroll
  for (int g = 0; g < GE; ++g) {
    const float d1 = sqrtf(d1s[g]);
    const float d2 = sqrtf(d2s[g]) / h0[g];
    const float h1 = (d1 <= 1e-15f && d2 <= 1e-15f)
                 ? fmaxf(1e-6f, h0[g] * 1e-3f)
                 : powf(0.01f / (d1 + d2), 0.2f);   // jax uses d1+d2 here
    dtv[g] = fminf(100.f * h0[g], h1);
    ptv[g] = tcur[g]; pdt[g] = dtv[g];
    act[g] = (tcur[g] < tfin[g]) && (dtv[g] > 0.f);
  }
#pragma unroll
  for (int l = 0; l < 2; ++l) { py[l] = y[l]; pf[l] = f[l]; ym[l] = y[l]; }

  // ---- adaptive stepping loop ----
  float k2[2], k3[2], k4v[2], k5[2], k6[2], k7[2], y1v[2];
  for (int iter = 0; iter < 4000; ++iter) {
    if (!(act[0] || act[1])) break;

#pragma unroll
    for (int l = 0; l < 2; ++l) yin[l] = y[l] + dtv[eh] * (SB10 * f[l]);
    drift(yin, k2);

#pragma unroll
    for (int l = 0; l < 2; ++l)
      yin[l] = y[l] + dtv[eh] * (SB20 * f[l] + SB21 * k2[l]);
    drift(yin, k3);

#pragma unroll
    for (int l = 0; l < 2; ++l)
      yin[l] = y[l] + dtv[eh] * (SB30 * f[l] + SB31 * k2[l] + SB32 * k3[l]);
    drift(yin, k4v);

#pragma unroll
    for (int l = 0; l < 2; ++l)
      yin[l] = y[l] + dtv[eh] * (SB40 * f[l] + SB41 * k2[l] + SB42 * k3[l] + SB43 * k4v[l]);
    drift(yin, k5);

#pragma unroll
    for (int l = 0; l < 2; ++l)
      yin[l] = y[l] + dtv[eh] * (SB50 * f[l] + SB51 * k2[l] + SB52 * k3[l] + SB53 * k4v[l] + SB54 * k5[l]);
    drift(yin, k6);

#pragma unroll
    for (int l = 0; l < 2; ++l)
      y1v[l] = y[l] + dtv[eh] * (CS0 * f[l] + CS2 * k3[l] + CS3 * k4v[l] + CS4 * k5[l] + CS5 * k6[l]);
    drift(y1v, k7);

    float rs[GE] = {0.f, 0.f};
#pragma unroll
    for (int l = 0; l < 2; ++l) {
      const float yerr = dtv[eh] * (CE0 * f[l] + CE2 * k3[l] + CE3 * k4v[l] + CE4 * k5[l] + CE5 * k6[l] + CE6 * k7[l]);
      const float tol = ATOL_C + RTOL_C * fmaxf(fabsf(y[l]), fabsf(y1v[l]));
      const float r = yerr / tol;
      rs[eh] += r * r;
    }
    float rsum[GE];
    blocksum(rs, rsum);

    bool acc[GE];
#pragma unroll
    for (int g = 0; g < GE; ++g)
      acc[g] = act[g] && (sqrtf(rsum[g] * (1.0f / Hd)) <= 1.0f);

    if (acc[eh]) {
#pragma unroll
      for (int l = 0; l < 2; ++l) {
        ym[l] = y[l] + dtv[eh] * (CM0 * f[l] + CM2 * k3[l] + CM3 * k4v[l] + CM4 * k5[l] + CM5 * k6[l] + CM6 * k7[l]);
        py[l] = y[l]; pf[l] = f[l];
        y[l] = y1v[l]; f[l] = k7[l];
      }
    }
#pragma unroll
    for (int g = 0; g < GE; ++g) {
      if (!act[g]) continue;
      const float er = sqrtf(rsum[g] * (1.0f / Hd));
      if (acc[g]) {
        ptv[g] = tcur[g]; pdt[g] = dtv[g];
        tcur[g] = tcur[g] + dtv[g];
      }
      float dtn;
      if (er == 0.0f) {
        dtn = dtv[g] * 10.0f;
      } else {
        const float dfac = (er < 1.0f) ? 1.0f : 0.2f;
        const float fac = fminf(10.0f, fmaxf(0.9f * powf(er, -0.2f), dfac));
        dtn = dtv[g] * fac;
      }
      dtv[g] = fmaxf(dtn, 0.0f);
      act[g] = (tcur[g] < tfin[g]) && (dtv[g] > 0.0f);
    }
  }

  // ---- interpolate at t_final (4th-order fit) and fused FC ----
  const float fcwA = fcW[jj];
  const float fcwB = fcW[j1];
  float s[GE] = {0.f, 0.f};
#pragma unroll
  for (int l = 0; l < 2; ++l) {
    const float denom = tcur[eh] - ptv[eh];
    const float xr = (tfin[eh] - ptv[eh]) / denom;
    const float dy0 = pdt[eh] * pf[l];
    const float dy1 = pdt[eh] * f[l];
    const float aa = -2.f * dy0 + 2.f * dy1 - 8.f * py[l] - 8.f * y[l] + 16.f * ym[l];
    const float bb =  5.f * dy0 - 3.f * dy1 + 18.f * py[l] + 14.f * y[l] - 32.f * ym[l];
    const float cc = -4.f * dy0 + 1.f * dy1 - 11.f * py[l] - 5.f * y[l] + 16.f * ym[l];
    const float dd = dy0;
    const float ee = py[l];
    const float yf = (((aa * xr + bb) * xr + cc) * xr + dd) * xr + ee;
    s[eh] += yf * ((l == 1) ? fcwB : fcwA);
  }
  float ssum[GE];
  blocksum(s, ssum);
  if (tid == 0) {
#pragma unroll
    for (int g = 0; g < GE; ++g) {
      float o = ssum[g] + fcb[0];
#pragma unroll
      for (int m = 0; m < MET; ++m) o += meta[(bg0 + g) * MET + m] * fcW[Hd + m];
      outp[bg0 + g] = o;
    }
  }
}

// ---------------- host launcher ----------------
extern "C" void kernel_launch(void* const* d_in, const int* in_sizes, int n_in,
                              void* d_out, int out_size, void* d_ws, size_t ws_size,
                              hipStream_t stream)
{
  (void)in_sizes; (void)n_in; (void)out_size; (void)ws_size;

  const float* x    = (const float*)d_in[0];
  const float* meta = (const float*)d_in[1];
  const float* eps  = (const float*)d_in[2];
  const float* gWih = (const float*)d_in[3];
  const float* gWhh = (const float*)d_in[4];
  const float* gbih = (const float*)d_in[5];
  const float* gbhh = (const float*)d_in[6];
  const float* eW1  = (const float*)d_in[7];
  const float* eb1  = (const float*)d_in[8];
  const float* eW2  = (const float*)d_in[9];
  const float* eb2  = (const float*)d_in[10];
  const float* oW1  = (const float*)d_in[11];
  const float* ob1  = (const float*)d_in[12];
  const float* oW2  = (const float*)d_in[13];
  const float* ob2  = (const float*)d_in[14];
  const float* fcW  = (const float*)d_in[15];
  const float* fcb  = (const float*)d_in[16];
  float* out = (float*)d_out;
  float* ws  = (float*)d_ws;

  // ws layout (floats)
  float* WhhP = ws + 0;          //  786432
  float* WihT = ws + 786432;     //   12288
  float* eW1P = ws + 798720;     //  262144
  float* eW2P = ws + 1060864;    //  524288
  float* oW1P = ws + 1585152;    //  262144
  float* oW2P = ws + 1847296;    //  262144
  float* hA   = ws + 2109440;    //  262144 (h ping / z0)
  float* hB   = ws + 2371584;    //  262144 (h pong / o1)

  pack_kT4<<<(H3d * Hd + 255) / 256, 256, 0, stream>>>(gWhh, WhhP, H3d, Hd);
  transpose_k<<<(H3d * 8 + 255) / 256, 256, 0, stream>>>(gWih, WihT, H3d, 8);
  pack_kT4<<<(Hd * Hd + 255) / 256, 256, 0, stream>>>(eW1, eW1P, Hd, Hd);
  pack_kT4<<<(1024 * Hd + 255) / 256, 256, 0, stream>>>(eW2, eW2P, 1024, Hd);
  pack_kT4<<<(Hd * Hd + 255) / 256, 256, 0, stream>>>(oW1, oW1P, Hd, Hd);
  pack_kT4<<<(Hd * Hd + 255) / 256, 256, 0, stream>>>(oW2, oW2P, Hd, Hd);
  hipMemsetAsync(hA, 0, (size_t)Bsz * Hd * sizeof(float), stream);

  // per-step GRU: 256 blocks x 512 threads, j-tiled (min per-CU L1 traffic)
  dim3 ggrid(32, 8);
  for (int t = 0; t < Nseq; ++t) {
    const float* hin = (t & 1) ? hB : hA;
    float* hout      = (t & 1) ? hA : hB;
    gru_step_kernel<<<ggrid, 512, 0, stream>>>(x, meta, WihT, WhhP, gbih, gbhh, hin, hout, t);
  }
  // final h in hA (t=63 odd writes hA)
  dim3 egrid(32, 8);
  gemm_relu_kernel<<<egrid, 256, 0, stream>>>(hA, eW1P, eb1, hB);           // o1 -> hB
  enc2_z0_kernel<<<egrid, 256, 0, stream>>>(hB, eW2P, eb2, eps, hA);        // z0 -> hA
  ode_fc_kernel<<<Bsz / 2, 512, 0, stream>>>(x, meta, hA, oW1P, ob1, oW2P, ob2, fcW, fcb, out);
}